// Round 1
// baseline (1502.414 us; speedup 1.0000x reference)
//
#include <hip/hip_runtime.h>
#include <math.h>

#define NN   20000
#define NE   320000
#define NH   4
#define NREL 40
#define FIN  768
#define HIDD 128
#define NCLS 9

__device__ __forceinline__ float lrelu(float v, float s) { return v > 0.f ? v : v * s; }

// ---------------- utility ----------------
__global__ void k_zero(float* p, int n) {
    int i = blockIdx.x * blockDim.x + threadIdx.x;
    if (i < n) p[i] = 0.f;
}
__global__ void k_copy_i32(int* d, const int* s, int n) {
    int i = blockIdx.x * blockDim.x + threadIdx.x;
    if (i < n) d[i] = s[i];
}

// ---------------- CSR build ----------------
__global__ void k_count(const int* __restrict__ dst, int* __restrict__ counts) {
    int e = blockIdx.x * blockDim.x + threadIdx.x;
    if (e < NE) atomicAdd(&counts[dst[e]], 1);
}
// single block, 1024 threads, chunk=20 -> covers 20000
__global__ void k_scan(const int* __restrict__ counts, int* __restrict__ rowptr) {
    __shared__ int sh[1024];
    int t = threadIdx.x;
    int base = t * 20;
    int sum = 0;
    if (t < 1000) {
        for (int k = 0; k < 20; ++k) sum += counts[base + k];
    }
    sh[t] = sum;
    __syncthreads();
    for (int off = 1; off < 1024; off <<= 1) {
        int v = (t >= off) ? sh[t - off] : 0;
        __syncthreads();
        sh[t] += v;
        __syncthreads();
    }
    int ex = (t == 0) ? 0 : sh[t - 1];
    if (t == 0) rowptr[0] = 0;
    if (t < 1000) {
        int run = ex;
        for (int k = 0; k < 20; ++k) {
            run += counts[base + k];
            rowptr[base + k + 1] = run;
        }
    }
}
__global__ void k_fill(const int* __restrict__ dst, int* __restrict__ cursor, int* __restrict__ eidx) {
    int e = blockIdx.x * blockDim.x + threadIdx.x;
    if (e < NE) {
        int pos = atomicAdd(&cursor[dst[e]], 1);
        eidx[pos] = e;
    }
}

// ---------------- small tables ----------------
// etab[tab][t][h] = rel[t,:2] . aedge[h,:2]   (tab: 0=conv0, 1..3=mid, 4=final)
__global__ void k_etab(const float* __restrict__ rel0, const float* __restrict__ relm,
                       const float* __restrict__ relL, const float* __restrict__ ae0,
                       const float* __restrict__ aem, const float* __restrict__ aeL,
                       float* __restrict__ etab) {
    int id = blockIdx.x * blockDim.x + threadIdx.x;
    if (id >= 5 * NREL * NH) return;
    int tab = id / (NREL * NH);
    int rem = id % (NREL * NH);
    int t = rem >> 2, h = rem & 3;
    const float *rel, *ae;
    if (tab == 0)      { rel = rel0;                     ae = ae0; }
    else if (tab <= 3) { rel = relm + (tab - 1) * NREL * 2; ae = aem + (tab - 1) * NH * 2; }
    else               { rel = relL;                     ae = aeL; }
    etab[id] = rel[t * 2] * ae[h * 2] + rel[t * 2 + 1] * ae[h * 2 + 1];
}
// wsm[i][h][f] = sum_o Wm[i,h,f,o] * asrcm[i,h,o]  (and wdm with adstm)
__global__ void k_wsm(const float* __restrict__ Wm, const float* __restrict__ asrcm,
                      const float* __restrict__ adstm, float* __restrict__ wsm,
                      float* __restrict__ wdm) {
    int id = blockIdx.x * blockDim.x + threadIdx.x;
    if (id >= 2 * 3 * NH * HIDD) return;
    int which = id / (3 * NH * HIDD);
    int r = id % (3 * NH * HIDD);
    int ih = r / HIDD;   // i*4+h
    int f = r % HIDD;
    const float* w = Wm + ((size_t)ih * HIDD + f) * HIDD;
    const float* a = (which ? adstm : asrcm) + ih * HIDD;
    float acc = 0.f;
    for (int o = 0; o < HIDD; ++o) acc += w[o] * a[o];
    (which ? wdm : wsm)[r] = acc;
}

// ---------------- tiled fp32 GEMM (64x64 tile, 4x4 per thread, BK=16) ----------------
// C[M, ldc], per blockIdx.y: head = nb/ntilesPerHead, Bbase = B + head*kPerHead*ldb + (nb%ntiles)*64
__global__ __launch_bounds__(256) void k_gemm(
    const float* __restrict__ A, int lda, const float* __restrict__ B, int ldb,
    int kPerHead, int ntilesPerHead, float* __restrict__ C, int ldc, int M, int K,
    float scl, const float* __restrict__ bias, const float* __restrict__ resid) {
    __shared__ float As[16][68];
    __shared__ float Bs[16][68];
    int tid = threadIdx.x;
    int row0 = blockIdx.x * 64;
    int nb = blockIdx.y;
    int head = nb / ntilesPerHead;
    int nt = nb % ntilesPerHead;
    const float* Bbase = B + (size_t)head * kPerHead * ldb + nt * 64;
    int col0 = nb * 64;
    int tr = tid >> 4, tc = tid & 15;
    int arow = tid >> 2;
    int akseg = (tid & 3) << 2;
    int bk = tid >> 4;
    int bn = (tid & 15) << 2;
    float acc[4][4];
#pragma unroll
    for (int i = 0; i < 4; ++i)
#pragma unroll
        for (int j = 0; j < 4; ++j) acc[i][j] = 0.f;

    for (int kt = 0; kt < K; kt += 16) {
        float4 av = make_float4(0.f, 0.f, 0.f, 0.f);
        int m = row0 + arow;
        if (m < M) av = *(const float4*)(A + (size_t)m * lda + kt + akseg);
        float4 bv = *(const float4*)(Bbase + (size_t)(kt + bk) * ldb + bn);
        __syncthreads();
        As[akseg + 0][arow] = av.x;
        As[akseg + 1][arow] = av.y;
        As[akseg + 2][arow] = av.z;
        As[akseg + 3][arow] = av.w;
        *(float4*)&Bs[bk][bn] = bv;
        __syncthreads();
#pragma unroll
        for (int kk = 0; kk < 16; ++kk) {
            float4 a = *(const float4*)&As[kk][tr << 2];
            float4 b = *(const float4*)&Bs[kk][tc << 2];
            acc[0][0] += a.x * b.x; acc[0][1] += a.x * b.y; acc[0][2] += a.x * b.z; acc[0][3] += a.x * b.w;
            acc[1][0] += a.y * b.x; acc[1][1] += a.y * b.y; acc[1][2] += a.y * b.z; acc[1][3] += a.y * b.w;
            acc[2][0] += a.z * b.x; acc[2][1] += a.z * b.y; acc[2][2] += a.z * b.z; acc[2][3] += a.z * b.w;
            acc[3][0] += a.w * b.x; acc[3][1] += a.w * b.y; acc[3][2] += a.w * b.z; acc[3][3] += a.w * b.w;
        }
    }
    int c0 = col0 + (tc << 2);
#pragma unroll
    for (int i = 0; i < 4; ++i) {
        int r = row0 + (tr << 2) + i;
        if (r < M) {
            float4 v;
            v.x = acc[i][0] * scl; v.y = acc[i][1] * scl;
            v.z = acc[i][2] * scl; v.w = acc[i][3] * scl;
            if (bias) {
                v.x += bias[c0]; v.y += bias[c0 + 1]; v.z += bias[c0 + 2]; v.w += bias[c0 + 3];
            }
            if (resid) {
                float4 rv = *(const float4*)(resid + (size_t)r * ldc + c0);
                v.x += rv.x; v.y += rv.y; v.z += rv.z; v.w += rv.w;
            }
            *(float4*)(C + (size_t)r * ldc + c0) = v;
        }
    }
}

// ---------------- attention scores (conv0 from h0 segments, mid from hb) ----------------
__global__ __launch_bounds__(128) void k_scores(
    const float* __restrict__ X, int xstride, int headseg, const float* __restrict__ Ws,
    const float* __restrict__ Wd, float* __restrict__ es, float* __restrict__ ed) {
    __shared__ float ss[128], sd[128];
    int n = blockIdx.x;
    int t = threadIdx.x;
    int h = t >> 5, lane = t & 31;
    int xoff = n * xstride + (headseg ? h * HIDD : 0) + (lane << 2);
    float4 xv = *(const float4*)(X + xoff);
    float4 wv = *(const float4*)(Ws + h * HIDD + (lane << 2));
    float4 dv = *(const float4*)(Wd + h * HIDD + (lane << 2));
    ss[t] = xv.x * wv.x + xv.y * wv.y + xv.z * wv.z + xv.w * wv.w;
    sd[t] = xv.x * dv.x + xv.y * dv.y + xv.z * dv.z + xv.w * dv.w;
    __syncthreads();
    for (int off = 16; off > 0; off >>= 1) {
        if (lane < off) { ss[t] += ss[t + off]; sd[t] += sd[t + off]; }
        __syncthreads();
    }
    if (lane == 0) { es[n * 4 + h] = ss[t]; ed[n * 4 + h] = sd[t]; }
}
__global__ void k_scoresL(const float* __restrict__ hL, const float* __restrict__ aS,
                          const float* __restrict__ aD, float* __restrict__ es,
                          float* __restrict__ ed) {
    int n = blockIdx.x * blockDim.x + threadIdx.x;
    if (n >= NN) return;
    for (int h = 0; h < NH; ++h) {
        float s = 0.f, d = 0.f;
        for (int c = 0; c < NCLS; ++c) {
            float v = hL[(size_t)n * 36 + h * 9 + c];
            s += v * aS[h * 9 + c];
            d += v * aD[h * 9 + c];
        }
        es[n * 4 + h] = s;
        ed[n * 4 + h] = d;
    }
}

// ---------------- edge softmax (no segment-max needed: |logit| << 10) ----------------
__global__ void k_edge1(const int* __restrict__ src, const int* __restrict__ dst,
                        const int* __restrict__ et, const float* __restrict__ es,
                        const float* __restrict__ ed, const float* __restrict__ etab,
                        float* __restrict__ exbuf, float* __restrict__ den) {
    int e = blockIdx.x * blockDim.x + threadIdx.x;
    if (e >= NE) return;
    int s = src[e], d = dst[e], t = et[e];
    float4 a = ((const float4*)es)[s];
    float4 b = ((const float4*)ed)[d];
    float4 c = ((const float4*)etab)[t];
    float4 ex;
    ex.x = expf(lrelu(a.x + b.x + c.x, 0.2f));
    ex.y = expf(lrelu(a.y + b.y + c.y, 0.2f));
    ex.z = expf(lrelu(a.z + b.z + c.z, 0.2f));
    ex.w = expf(lrelu(a.w + b.w + c.w, 0.2f));
    ((float4*)exbuf)[e] = ex;
    atomicAdd(&den[d * 4 + 0], ex.x);
    atomicAdd(&den[d * 4 + 1], ex.y);
    atomicAdd(&den[d * 4 + 2], ex.z);
    atomicAdd(&den[d * 4 + 3], ex.w);
}
__global__ void k_edge2(const int* __restrict__ dst, const int* __restrict__ dist,
                        const float* __restrict__ den, float* __restrict__ exbuf) {
    int e = blockIdx.x * blockDim.x + threadIdx.x;
    if (e >= NE) return;
    int d = dst[e];
    float4 ex = ((float4*)exbuf)[e];
    float4 dn = ((const float4*)den)[d];
    float w = 1.f / (1.f + (float)dist[e]);
    ex.x = ex.x / (dn.x + 1e-16f) * w;
    ex.y = ex.y / (dn.y + 1e-16f) * w;
    ex.z = ex.z / (dn.z + 1e-16f) * w;
    ex.w = ex.w / (dn.w + 1e-16f) * w;
    ((float4*)exbuf)[e] = ex;
}

// ---------------- aggregation (CSR, one block per node) ----------------
// conv0: transform-first; fuse head-mean + bias
__global__ __launch_bounds__(128) void k_agg0(
    const int* __restrict__ rowptr, const int* __restrict__ eidx, const int* __restrict__ src,
    const float* __restrict__ alpha, const float* __restrict__ h0,
    const float* __restrict__ b0, float* __restrict__ xout) {
    int n = blockIdx.x, t = threadIdx.x;
    int p0 = rowptr[n], p1 = rowptr[n + 1];
    float acc = 0.f;
    for (int p = p0; p < p1; ++p) {
        int e = eidx[p];
        int s = src[e];
        float4 al = ((const float4*)alpha)[e];
        const float* hr = h0 + (size_t)s * 512;
        acc += al.x * hr[t] + al.y * hr[128 + t] + al.z * hr[256 + t] + al.w * hr[384 + t];
    }
    xout[(size_t)n * HIDD + t] = 0.25f * acc + b0[t];
}
// mid: aggregate-first (gather 128/edge, shared across heads)
__global__ __launch_bounds__(128) void k_aggmid(
    const int* __restrict__ rowptr, const int* __restrict__ eidx, const int* __restrict__ src,
    const float* __restrict__ alpha, const float* __restrict__ hb, float* __restrict__ agg) {
    int n = blockIdx.x, t = threadIdx.x;
    int p0 = rowptr[n], p1 = rowptr[n + 1];
    float a0 = 0.f, a1 = 0.f, a2 = 0.f, a3 = 0.f;
    for (int p = p0; p < p1; ++p) {
        int e = eidx[p];
        int s = src[e];
        float4 al = ((const float4*)alpha)[e];
        float v = hb[(size_t)s * HIDD + t];
        a0 += al.x * v; a1 += al.y * v; a2 += al.z * v; a3 += al.w * v;
    }
    float* o = agg + (size_t)n * 512;
    o[t] = a0; o[128 + t] = a1; o[256 + t] = a2; o[384 + t] = a3;
}
// final: transform-first (36 floats/edge); fuse mean + bias + lrelu(0.1)
__global__ __launch_bounds__(64) void k_aggL(
    const int* __restrict__ rowptr, const int* __restrict__ eidx, const int* __restrict__ src,
    const float* __restrict__ alpha, const float* __restrict__ hL,
    const float* __restrict__ bL, float* __restrict__ out) {
    __shared__ float sh[36];
    int n = blockIdx.x, t = threadIdx.x;
    int p0 = rowptr[n], p1 = rowptr[n + 1];
    if (t < 36) {
        int hh = t / 9;
        float acc = 0.f;
        for (int p = p0; p < p1; ++p) {
            int e = eidx[p];
            int s = src[e];
            acc += alpha[e * 4 + hh] * hL[(size_t)s * 36 + t];
        }
        sh[t] = acc;
    }
    __syncthreads();
    if (t < 9) {
        float v = 0.25f * (sh[t] + sh[t + 9] + sh[t + 18] + sh[t + 27]) + bL[t];
        out[(size_t)n * 9 + t] = lrelu(v, 0.1f);
    }
}

// ---------------- batchnorm (training mode, batch stats) ----------------
__global__ __launch_bounds__(128) void k_bnstats(const float* __restrict__ x, float* __restrict__ sums) {
    int f = threadIdx.x;
    float s = 0.f, q = 0.f;
    for (int r = blockIdx.x; r < NN; r += gridDim.x) {
        float v = x[(size_t)r * HIDD + f];
        s += v;
        q += v * v;
    }
    atomicAdd(&sums[f], s);
    atomicAdd(&sums[128 + f], q);
}
__global__ void k_bnfinal(const float* __restrict__ sums, const float* __restrict__ gamma,
                          const float* __restrict__ beta, float* __restrict__ scale,
                          float* __restrict__ shift) {
    int f = threadIdx.x;
    float m = sums[f] * (1.f / NN);
    float v = sums[128 + f] * (1.f / NN) - m * m;
    float sc = gamma[f] * rsqrtf(v + 1e-5f);
    scale[f] = sc;
    shift[f] = beta[f] - m * sc;
}
__global__ void k_bnapply(const float* __restrict__ x, const float* __restrict__ scale,
                          const float* __restrict__ shift, float* __restrict__ hb) {
    int i = blockIdx.x * blockDim.x + threadIdx.x;  // float4 index
    if (i >= NN * HIDD / 4) return;
    int c = i & 31;
    float4 v = ((const float4*)x)[i];
    float4 sc = ((const float4*)scale)[c];
    float4 sh = ((const float4*)shift)[c];
    float4 y;
    y.x = lrelu(v.x * sc.x + sh.x, 0.1f);
    y.y = lrelu(v.y * sc.y + sh.y, 0.1f);
    y.z = lrelu(v.z * sc.z + sh.z, 0.1f);
    y.w = lrelu(v.w * sc.w + sh.w, 0.1f);
    ((float4*)hb)[i] = y;
}

// ---------------- final small GEMM: hL = hb @ WLcat  [N,36] ----------------
__global__ __launch_bounds__(64) void k_gemmL(const float* __restrict__ hb,
                                              const float* __restrict__ WL,
                                              float* __restrict__ hL) {
    __shared__ float row[128];
    int n = blockIdx.x, t = threadIdx.x;
    row[t] = hb[(size_t)n * HIDD + t];
    row[t + 64] = hb[(size_t)n * HIDD + t + 64];
    __syncthreads();
    if (t < 36) {
        int h = t / 9, c = t - h * 9;
        const float* w = WL + h * (HIDD * NCLS) + c;
        float acc = 0.f;
#pragma unroll 8
        for (int k = 0; k < HIDD; ++k) acc += row[k] * w[k * NCLS];
        hL[(size_t)n * 36 + t] = acc;
    }
}

extern "C" void kernel_launch(void* const* d_in, const int* in_sizes, int n_in,
                              void* d_out, int out_size, void* d_ws, size_t ws_size,
                              hipStream_t stream) {
    const float* x = (const float*)d_in[0];
    const int* ei = (const int*)d_in[1];
    const int* src = ei;
    const int* dstp = ei + NE;
    const int* etp = (const int*)d_in[2];
    const int* edist = (const int*)d_in[3];
    const float* W0 = (const float*)d_in[4];
    const float* asrc0 = (const float*)d_in[5];
    const float* adst0 = (const float*)d_in[6];
    const float* aedge0 = (const float*)d_in[7];
    const float* b0 = (const float*)d_in[8];
    const float* rel0 = (const float*)d_in[9];
    const float* Wm = (const float*)d_in[10];
    const float* asrcm = (const float*)d_in[11];
    const float* adstm = (const float*)d_in[12];
    const float* aedgem = (const float*)d_in[13];
    const float* bm = (const float*)d_in[14];
    const float* relm = (const float*)d_in[15];
    const float* WL = (const float*)d_in[16];
    const float* asrcL = (const float*)d_in[17];
    const float* adstL = (const float*)d_in[18];
    const float* aedgeL = (const float*)d_in[19];
    const float* bL = (const float*)d_in[20];
    const float* relL = (const float*)d_in[21];
    const float* bng = (const float*)d_in[22];
    const float* bnb = (const float*)d_in[23];
    float* out = (float*)d_out;

    char* w = (char*)d_ws;
    size_t off = 0;
    auto alloc = [&](size_t bytes) -> char* {
        char* p = w + off;
        off = (off + bytes + 255) & ~(size_t)255;
        return p;
    };
    float* h0 = (float*)alloc((size_t)NN * 512 * 4);     // h0 / agg / hL (reused)
    float* xbuf = (float*)alloc((size_t)NN * HIDD * 4);  // node features between layers
    float* hb = (float*)alloc((size_t)NN * HIDD * 4);    // lrelu(BN(x))
    float* exbuf = (float*)alloc((size_t)NE * 4 * 4);    // exp(logit) then alpha (in-place)
    float* es = (float*)alloc((size_t)NN * 4 * 4);
    float* ed = (float*)alloc((size_t)NN * 4 * 4);
    float* den = (float*)alloc((size_t)NN * 4 * 4);
    float* bnsums = (float*)alloc(256 * 4);
    float* scale = (float*)alloc(128 * 4);
    float* shift = (float*)alloc(128 * 4);
    float* wsmb = (float*)alloc(1536 * 4);
    float* wdmb = (float*)alloc(1536 * 4);
    float* etab = (float*)alloc(800 * 4);
    int* counts = (int*)alloc((size_t)NN * 4);
    int* rowptr = (int*)alloc((size_t)(NN + 1) * 4);
    int* cursor = (int*)alloc((size_t)NN * 4);
    int* eidx = (int*)alloc((size_t)NE * 4);

    const int B256 = 256;
    int gNE = (NE + 255) / 256;
    int gNN = (NN + 255) / 256;

    // CSR build (once; reused by all 5 convs)
    k_zero<<<gNN, B256, 0, stream>>>((float*)counts, NN);
    k_count<<<gNE, B256, 0, stream>>>(dstp, counts);
    k_scan<<<1, 1024, 0, stream>>>(counts, rowptr);
    k_copy_i32<<<gNN, B256, 0, stream>>>(cursor, rowptr, NN);
    k_fill<<<gNE, B256, 0, stream>>>(dstp, cursor, eidx);

    // small tables
    k_etab<<<4, B256, 0, stream>>>(rel0, relm, relL, aedge0, aedgem, aedgeL, etab);
    k_wsm<<<12, B256, 0, stream>>>(Wm, asrcm, adstm, wsmb, wdmb);

    // ---- conv0: transform-first ----
    {
        dim3 g0((NN + 63) / 64, 8);
        k_gemm<<<g0, 256, 0, stream>>>(x, FIN, W0, HIDD, FIN, 2, h0, 512, NN, FIN, 1.f,
                                       nullptr, nullptr);
        k_scores<<<NN, 128, 0, stream>>>(h0, 512, 1, asrc0, adst0, es, ed);
        k_zero<<<(NN * 4 + 255) / 256, B256, 0, stream>>>(den, NN * 4);
        k_edge1<<<gNE, B256, 0, stream>>>(src, dstp, etp, es, ed, etab + 0, exbuf, den);
        k_edge2<<<gNE, B256, 0, stream>>>(dstp, edist, den, exbuf);
        k_agg0<<<NN, 128, 0, stream>>>(rowptr, eidx, src, exbuf, h0, b0, xbuf);
    }

    // ---- 3 middle convs: aggregate-first ----
    for (int i = 0; i < 3; ++i) {
        k_zero<<<1, 256, 0, stream>>>(bnsums, 256);
        k_bnstats<<<200, 128, 0, stream>>>(xbuf, bnsums);
        k_bnfinal<<<1, 128, 0, stream>>>(bnsums, bng + i * 128, bnb + i * 128, scale, shift);
        k_bnapply<<<(NN * HIDD / 4 + 255) / 256, B256, 0, stream>>>(xbuf, scale, shift, hb);
        k_scores<<<NN, 128, 0, stream>>>(hb, HIDD, 0, wsmb + i * 512, wdmb + i * 512, es, ed);
        k_zero<<<(NN * 4 + 255) / 256, B256, 0, stream>>>(den, NN * 4);
        k_edge1<<<gNE, B256, 0, stream>>>(src, dstp, etp, es, ed, etab + (1 + i) * 160, exbuf, den);
        k_edge2<<<gNE, B256, 0, stream>>>(dstp, edist, den, exbuf);
        k_aggmid<<<NN, 128, 0, stream>>>(rowptr, eidx, src, exbuf, hb, h0);
        dim3 gm((NN + 63) / 64, 2);
        // x_{i+1} = 0.25 * agg @ Wm[i](as [512,128]) + bm[i] + hb   (mean+bias+residual fused)
        k_gemm<<<gm, 256, 0, stream>>>(h0, 512, Wm + (size_t)i * 4 * HIDD * HIDD, HIDD, 512, 2,
                                       xbuf, HIDD, NN, 512, 0.25f, bm + i * 128, hb);
    }

    // ---- final conv: transform-first (36-wide) ----
    {
        k_zero<<<1, 256, 0, stream>>>(bnsums, 256);
        k_bnstats<<<200, 128, 0, stream>>>(xbuf, bnsums);
        k_bnfinal<<<1, 128, 0, stream>>>(bnsums, bng + 3 * 128, bnb + 3 * 128, scale, shift);
        k_bnapply<<<(NN * HIDD / 4 + 255) / 256, B256, 0, stream>>>(xbuf, scale, shift, hb);
        k_gemmL<<<NN, 64, 0, stream>>>(hb, WL, h0);  // h0 reused as hL [N,36]
        k_scoresL<<<gNN, B256, 0, stream>>>(h0, asrcL, adstL, es, ed);
        k_zero<<<(NN * 4 + 255) / 256, B256, 0, stream>>>(den, NN * 4);
        k_edge1<<<gNE, B256, 0, stream>>>(src, dstp, etp, es, ed, etab + 4 * 160, exbuf, den);
        k_edge2<<<gNE, B256, 0, stream>>>(dstp, edist, den, exbuf);
        k_aggL<<<NN, 64, 0, stream>>>(rowptr, eidx, src, exbuf, h0, bL, out);
    }
}

// Round 2
// 752.252 us; speedup vs baseline: 1.9972x; 1.9972x over previous
//
#include <hip/hip_runtime.h>
#include <math.h>

#define NN   20000
#define NE   320000
#define NH   4
#define NREL 40
#define FIN  768
#define HIDD 128
#define NCLS 9

typedef __attribute__((ext_vector_type(8))) short short8;
typedef __attribute__((ext_vector_type(4))) float f32x4;
typedef unsigned short b16;

__device__ __forceinline__ float lrelu(float v, float s) { return v > 0.f ? v : v * s; }
__device__ __forceinline__ b16 f2b(float f) {
    unsigned int u = __float_as_uint(f);
    unsigned int r = u + 0x7FFFu + ((u >> 16) & 1u);
    return (b16)(r >> 16);
}
__device__ __forceinline__ float b2f(b16 u) { return __uint_as_float(((unsigned int)u) << 16); }

// ---------------- utility ----------------
__global__ void k_zero(float* p, int n) {
    int i = blockIdx.x * blockDim.x + threadIdx.x;
    if (i < n) p[i] = 0.f;
}
__global__ void k_copy_i32(int* d, const int* s, int n) {
    int i = blockIdx.x * blockDim.x + threadIdx.x;
    if (i < n) d[i] = s[i];
}

// ---------------- CSR build ----------------
__global__ void k_count(const int* __restrict__ dst, int* __restrict__ counts) {
    int e = blockIdx.x * blockDim.x + threadIdx.x;
    if (e < NE) atomicAdd(&counts[dst[e]], 1);
}
__global__ void k_scan(const int* __restrict__ counts, int* __restrict__ rowptr) {
    __shared__ int sh[1024];
    int t = threadIdx.x;
    int base = t * 20;
    int sum = 0;
    if (t < 1000) for (int k = 0; k < 20; ++k) sum += counts[base + k];
    sh[t] = sum;
    __syncthreads();
    for (int off = 1; off < 1024; off <<= 1) {
        int v = (t >= off) ? sh[t - off] : 0;
        __syncthreads();
        sh[t] += v;
        __syncthreads();
    }
    int ex = (t == 0) ? 0 : sh[t - 1];
    if (t == 0) rowptr[0] = 0;
    if (t < 1000) {
        int run = ex;
        for (int k = 0; k < 20; ++k) {
            run += counts[base + k];
            rowptr[base + k + 1] = run;
        }
    }
}
__global__ void k_fill(const int* __restrict__ dst, int* __restrict__ cursor, int* __restrict__ eidx) {
    int e = blockIdx.x * blockDim.x + threadIdx.x;
    if (e < NE) {
        int pos = atomicAdd(&cursor[dst[e]], 1);
        eidx[pos] = e;
    }
}
// permute edge arrays into CSR order (sequential access in all later passes)
__global__ void k_permute(const int* __restrict__ eidx, const int* __restrict__ src,
                          const int* __restrict__ dst, const int* __restrict__ etype,
                          const int* __restrict__ dist, int* __restrict__ srcp,
                          int* __restrict__ dstp, int* __restrict__ etp,
                          float* __restrict__ distwp) {
    int p = blockIdx.x * blockDim.x + threadIdx.x;
    if (p >= NE) return;
    int e = eidx[p];
    srcp[p] = src[e];
    dstp[p] = dst[e];
    etp[p] = etype[e];
    distwp[p] = 1.f / (1.f + (float)dist[e]);
}

// ---------------- small tables ----------------
__global__ void k_etab(const float* __restrict__ rel0, const float* __restrict__ relm,
                       const float* __restrict__ relL, const float* __restrict__ ae0,
                       const float* __restrict__ aem, const float* __restrict__ aeL,
                       float* __restrict__ etab) {
    int id = blockIdx.x * blockDim.x + threadIdx.x;
    if (id >= 5 * NREL * NH) return;
    int tab = id / (NREL * NH);
    int rem = id % (NREL * NH);
    int t = rem >> 2, h = rem & 3;
    const float *rel, *ae;
    if (tab == 0)      { rel = rel0;                        ae = ae0; }
    else if (tab <= 3) { rel = relm + (tab - 1) * NREL * 2; ae = aem + (tab - 1) * NH * 2; }
    else               { rel = relL;                        ae = aeL; }
    etab[id] = rel[t * 2] * ae[h * 2] + rel[t * 2 + 1] * ae[h * 2 + 1];
}
__global__ void k_wsm(const float* __restrict__ Wm, const float* __restrict__ asrcm,
                      const float* __restrict__ adstm, float* __restrict__ wsm,
                      float* __restrict__ wdm) {
    int id = blockIdx.x * blockDim.x + threadIdx.x;
    if (id >= 2 * 3 * NH * HIDD) return;
    int which = id / (3 * NH * HIDD);
    int r = id % (3 * NH * HIDD);
    int ih = r / HIDD;
    int f = r % HIDD;
    const float* w = Wm + ((size_t)ih * HIDD + f) * HIDD;
    const float* a = (which ? adstm : asrcm) + ih * HIDD;
    float acc = 0.f;
    for (int o = 0; o < HIDD; ++o) acc += w[o] * a[o];
    (which ? wdm : wsm)[r] = acc;
}

// ---------------- bf16 conversions ----------------
__global__ void k_cast_bf16(const float* __restrict__ in, b16* __restrict__ out, int n4) {
    int i = blockIdx.x * blockDim.x + threadIdx.x;
    if (i >= n4) return;
    float4 v = ((const float4*)in)[i];
    ushort4 o;
    o.x = f2b(v.x); o.y = f2b(v.y); o.z = f2b(v.z); o.w = f2b(v.w);
    ((ushort4*)out)[i] = o;
}
// B0t[c][k] = W0[h][k][o], c = h*128+o   -> [512][768] bf16
__global__ void k_convB0(const float* __restrict__ W0, b16* __restrict__ B0t) {
    int id = blockIdx.x * blockDim.x + threadIdx.x;
    if (id >= 512 * FIN) return;
    int c = id / FIN, k = id % FIN;
    int h = c >> 7, o = c & 127;
    B0t[id] = f2b(W0[((size_t)h * FIN + k) * HIDD + o]);
}
// Bmt[i][o][hf] = Wm[i][hf][o]  -> 3 x [128][512] bf16
__global__ void k_convBm(const float* __restrict__ Wm, b16* __restrict__ Bmt) {
    int id = blockIdx.x * blockDim.x + threadIdx.x;
    if (id >= 3 * HIDD * 512) return;
    int i = id / (HIDD * 512);
    int r = id % (HIDD * 512);
    int o = r / 512, hf = r % 512;
    Bmt[id] = f2b(Wm[(size_t)i * 512 * HIDD + (size_t)hf * HIDD + o]);
}

// ---------------- MFMA bf16 GEMM: C = A[M,K] @ Bt[N,K]^T ----------------
// 128x128 tile, 4 waves (2x2), each wave 64x64 = 4x4 mfma_16x16x32 subtiles.
// Epilogue: Cb!=null -> bf16 store; else fp32 Cf = scl*acc + bias[c] + resid.
__global__ __launch_bounds__(256) void k_mfma_gemm(
    const b16* __restrict__ A, const b16* __restrict__ Bt, int M, int K, int N,
    float scl, b16* __restrict__ Cb, float* __restrict__ Cf,
    const float* __restrict__ bias, const float* __restrict__ resid) {
    __shared__ b16 As[128][40];   // +8 pad: conflict-free b128 reads
    __shared__ b16 Bs[128][40];
    int tid = threadIdx.x;
    int lane = tid & 63, wave = tid >> 6;
    int wm = wave >> 1, wn = wave & 1;
    int l16 = lane & 15, quad = lane >> 4;
    int row0 = blockIdx.x * 128, col0 = blockIdx.y * 128;

    int c0 = tid, c1 = tid + 256;
    int ar0 = c0 >> 2, as0 = (c0 & 3) << 3;
    int ar1 = c1 >> 2, as1 = (c1 & 3) << 3;
    bool va0 = (row0 + ar0) < M, va1 = (row0 + ar1) < M;
    const b16* Ap0 = A + (size_t)(row0 + ar0) * K + as0;
    const b16* Ap1 = A + (size_t)(row0 + ar1) * K + as1;
    const b16* Bp0 = Bt + (size_t)(col0 + ar0) * K + as0;
    const b16* Bp1 = Bt + (size_t)(col0 + ar1) * K + as1;

    f32x4 acc[4][4];
#pragma unroll
    for (int i = 0; i < 4; ++i)
#pragma unroll
        for (int j = 0; j < 4; ++j) acc[i][j] = (f32x4){0.f, 0.f, 0.f, 0.f};
    short8 zz = {0, 0, 0, 0, 0, 0, 0, 0};

    for (int kt = 0; kt < K; kt += 32) {
        short8 a0 = va0 ? *(const short8*)(Ap0 + kt) : zz;
        short8 a1 = va1 ? *(const short8*)(Ap1 + kt) : zz;
        short8 b0 = *(const short8*)(Bp0 + kt);
        short8 b1 = *(const short8*)(Bp1 + kt);
        __syncthreads();
        *(short8*)&As[ar0][as0] = a0;
        *(short8*)&As[ar1][as1] = a1;
        *(short8*)&Bs[ar0][as0] = b0;
        *(short8*)&Bs[ar1][as1] = b1;
        __syncthreads();
        short8 bf[4];
#pragma unroll
        for (int ni = 0; ni < 4; ++ni)
            bf[ni] = *(const short8*)&Bs[wn * 64 + ni * 16 + l16][quad * 8];
#pragma unroll
        for (int mi = 0; mi < 4; ++mi) {
            short8 af = *(const short8*)&As[wm * 64 + mi * 16 + l16][quad * 8];
#pragma unroll
            for (int ni = 0; ni < 4; ++ni)
                acc[mi][ni] = __builtin_amdgcn_mfma_f32_16x16x32_bf16(af, bf[ni], acc[mi][ni], 0, 0, 0);
        }
    }
    if (Cb) {
#pragma unroll
        for (int mi = 0; mi < 4; ++mi) {
            int rb = row0 + wm * 64 + mi * 16 + quad * 4;
#pragma unroll
            for (int ni = 0; ni < 4; ++ni) {
                int c = col0 + wn * 64 + ni * 16 + l16;
#pragma unroll
                for (int r = 0; r < 4; ++r) {
                    int row = rb + r;
                    if (row < M) Cb[(size_t)row * N + c] = f2b(acc[mi][ni][r]);
                }
            }
        }
    } else {
#pragma unroll
        for (int mi = 0; mi < 4; ++mi) {
            int rb = row0 + wm * 64 + mi * 16 + quad * 4;
#pragma unroll
            for (int ni = 0; ni < 4; ++ni) {
                int c = col0 + wn * 64 + ni * 16 + l16;
#pragma unroll
                for (int r = 0; r < 4; ++r) {
                    int row = rb + r;
                    if (row < M) {
                        float v = acc[mi][ni][r] * scl + bias[c] + resid[(size_t)row * N + c];
                        Cf[(size_t)row * N + c] = v;
                    }
                }
            }
        }
    }
}

// ---------------- attention scores ----------------
// conv0: from bf16 h0 [N][512] head segments
__global__ __launch_bounds__(128) void k_scores_b(
    const b16* __restrict__ h0b, const float* __restrict__ Ws,
    const float* __restrict__ Wd, float* __restrict__ es, float* __restrict__ ed) {
    __shared__ float ss[128], sd[128];
    int n = blockIdx.x, t = threadIdx.x;
    int h = t >> 5, ln = t & 31;
    ushort4 xv = *(const ushort4*)(h0b + (size_t)n * 512 + h * 128 + (ln << 2));
    float x0 = b2f(xv.x), x1 = b2f(xv.y), x2 = b2f(xv.z), x3 = b2f(xv.w);
    float4 wv = *(const float4*)(Ws + h * HIDD + (ln << 2));
    float4 dv = *(const float4*)(Wd + h * HIDD + (ln << 2));
    ss[t] = x0 * wv.x + x1 * wv.y + x2 * wv.z + x3 * wv.w;
    sd[t] = x0 * dv.x + x1 * dv.y + x2 * dv.z + x3 * dv.w;
    __syncthreads();
    for (int off = 16; off > 0; off >>= 1) {
        if (ln < off) { ss[t] += ss[t + off]; sd[t] += sd[t + off]; }
        __syncthreads();
    }
    if (ln == 0) { es[n * 4 + h] = ss[t]; ed[n * 4 + h] = sd[t]; }
}
// mid: from fp32 hb [N][128] with folded per-head vectors
__global__ __launch_bounds__(128) void k_scores_f(
    const float* __restrict__ X, const float* __restrict__ Ws,
    const float* __restrict__ Wd, float* __restrict__ es, float* __restrict__ ed) {
    __shared__ float ss[128], sd[128];
    int n = blockIdx.x, t = threadIdx.x;
    int h = t >> 5, ln = t & 31;
    float4 xv = *(const float4*)(X + (size_t)n * HIDD + (ln << 2));
    float4 wv = *(const float4*)(Ws + h * HIDD + (ln << 2));
    float4 dv = *(const float4*)(Wd + h * HIDD + (ln << 2));
    ss[t] = xv.x * wv.x + xv.y * wv.y + xv.z * wv.z + xv.w * wv.w;
    sd[t] = xv.x * dv.x + xv.y * dv.y + xv.z * dv.z + xv.w * dv.w;
    __syncthreads();
    for (int off = 16; off > 0; off >>= 1) {
        if (ln < off) { ss[t] += ss[t + off]; sd[t] += sd[t + off]; }
        __syncthreads();
    }
    if (ln == 0) { es[n * 4 + h] = ss[t]; ed[n * 4 + h] = sd[t]; }
}
__global__ void k_scoresL(const float* __restrict__ hL, const float* __restrict__ aS,
                          const float* __restrict__ aD, float* __restrict__ es,
                          float* __restrict__ ed) {
    int n = blockIdx.x * blockDim.x + threadIdx.x;
    if (n >= NN) return;
    for (int h = 0; h < NH; ++h) {
        float s = 0.f, d = 0.f;
        for (int c = 0; c < NCLS; ++c) {
            float v = hL[(size_t)n * 36 + h * 9 + c];
            s += v * aS[h * 9 + c];
            d += v * aD[h * 9 + c];
        }
        es[n * 4 + h] = s;
        ed[n * 4 + h] = d;
    }
}

// ---------------- edge exp (no atomics; den folded into agg) ----------------
__global__ void k_edge1(const int* __restrict__ srcp, const int* __restrict__ dstp,
                        const int* __restrict__ etp, const float* __restrict__ es,
                        const float* __restrict__ ed, const float* __restrict__ etab,
                        float* __restrict__ exbuf) {
    int p = blockIdx.x * blockDim.x + threadIdx.x;
    if (p >= NE) return;
    int s = srcp[p], d = dstp[p], t = etp[p];
    float4 a = ((const float4*)es)[s];
    float4 b = ((const float4*)ed)[d];
    float4 c = ((const float4*)etab)[t];
    float4 ex;
    ex.x = __expf(lrelu(a.x + b.x + c.x, 0.2f));
    ex.y = __expf(lrelu(a.y + b.y + c.y, 0.2f));
    ex.z = __expf(lrelu(a.z + b.z + c.z, 0.2f));
    ex.w = __expf(lrelu(a.w + b.w + c.w, 0.2f));
    ((float4*)exbuf)[p] = ex;
}

// ---------------- aggregation (CSR order, den computed in-block) ----------------
// conv0: gather bf16 h0 rows (512 wide), fuse softmax-norm + distw + head-mean + bias
__global__ __launch_bounds__(64) void k_agg0(
    const int* __restrict__ rowptr, const int* __restrict__ srcp,
    const float* __restrict__ exbuf, const float* __restrict__ distwp,
    const b16* __restrict__ h0b, const float* __restrict__ b0, float* __restrict__ xout) {
    int n = blockIdx.x, t = threadIdx.x;
    int p0 = rowptr[n], p1 = rowptr[n + 1];
    float d0 = 0.f, d1 = 0.f, d2 = 0.f, d3 = 0.f;
    for (int p = p0; p < p1; ++p) {
        float4 e = ((const float4*)exbuf)[p];
        d0 += e.x; d1 += e.y; d2 += e.z; d3 += e.w;
    }
    float r0 = 1.f / (d0 + 1e-16f), r1 = 1.f / (d1 + 1e-16f);
    float r2 = 1.f / (d2 + 1e-16f), r3 = 1.f / (d3 + 1e-16f);
    float acc0 = 0.f, acc1 = 0.f;
    int tt = t * 2;
    int p = p0;
    for (; p + 4 <= p1; p += 4) {
        int ss[4]; float4 ee[4]; float ww[4];
#pragma unroll
        for (int j = 0; j < 4; ++j) {
            ss[j] = srcp[p + j];
            ee[j] = ((const float4*)exbuf)[p + j];
            ww[j] = distwp[p + j];
        }
#pragma unroll
        for (int j = 0; j < 4; ++j) {
            const b16* hr = h0b + (size_t)ss[j] * 512;
            ushort2 u0 = *(const ushort2*)(hr + tt);
            ushort2 u1 = *(const ushort2*)(hr + 128 + tt);
            ushort2 u2 = *(const ushort2*)(hr + 256 + tt);
            ushort2 u3 = *(const ushort2*)(hr + 384 + tt);
            float c0 = ee[j].x * r0 * ww[j], c1 = ee[j].y * r1 * ww[j];
            float c2 = ee[j].z * r2 * ww[j], c3 = ee[j].w * r3 * ww[j];
            acc0 += c0 * b2f(u0.x) + c1 * b2f(u1.x) + c2 * b2f(u2.x) + c3 * b2f(u3.x);
            acc1 += c0 * b2f(u0.y) + c1 * b2f(u1.y) + c2 * b2f(u2.y) + c3 * b2f(u3.y);
        }
    }
    for (; p < p1; ++p) {
        int s = srcp[p];
        float4 e = ((const float4*)exbuf)[p];
        float w = distwp[p];
        const b16* hr = h0b + (size_t)s * 512;
        ushort2 u0 = *(const ushort2*)(hr + tt);
        ushort2 u1 = *(const ushort2*)(hr + 128 + tt);
        ushort2 u2 = *(const ushort2*)(hr + 256 + tt);
        ushort2 u3 = *(const ushort2*)(hr + 384 + tt);
        float c0 = e.x * r0 * w, c1 = e.y * r1 * w, c2 = e.z * r2 * w, c3 = e.w * r3 * w;
        acc0 += c0 * b2f(u0.x) + c1 * b2f(u1.x) + c2 * b2f(u2.x) + c3 * b2f(u3.x);
        acc1 += c0 * b2f(u0.y) + c1 * b2f(u1.y) + c2 * b2f(u2.y) + c3 * b2f(u3.y);
    }
    xout[(size_t)n * HIDD + tt] = 0.25f * acc0 + b0[tt];
    xout[(size_t)n * HIDD + tt + 1] = 0.25f * acc1 + b0[tt + 1];
}
// mid: gather bf16 hb rows (128 wide), produce bf16 agg [N][512] (GEMM A operand)
__global__ __launch_bounds__(64) void k_aggmid(
    const int* __restrict__ rowptr, const int* __restrict__ srcp,
    const float* __restrict__ exbuf, const float* __restrict__ distwp,
    const b16* __restrict__ hbb, b16* __restrict__ aggb) {
    int n = blockIdx.x, t = threadIdx.x;
    int p0 = rowptr[n], p1 = rowptr[n + 1];
    float d0 = 0.f, d1 = 0.f, d2 = 0.f, d3 = 0.f;
    for (int p = p0; p < p1; ++p) {
        float4 e = ((const float4*)exbuf)[p];
        d0 += e.x; d1 += e.y; d2 += e.z; d3 += e.w;
    }
    float r0 = 1.f / (d0 + 1e-16f), r1 = 1.f / (d1 + 1e-16f);
    float r2 = 1.f / (d2 + 1e-16f), r3 = 1.f / (d3 + 1e-16f);
    float a00 = 0.f, a01 = 0.f, a10 = 0.f, a11 = 0.f;
    float a20 = 0.f, a21 = 0.f, a30 = 0.f, a31 = 0.f;
    int tt = t * 2;
    int p = p0;
    for (; p + 4 <= p1; p += 4) {
        int ss[4]; float4 ee[4]; float ww[4];
#pragma unroll
        for (int j = 0; j < 4; ++j) {
            ss[j] = srcp[p + j];
            ee[j] = ((const float4*)exbuf)[p + j];
            ww[j] = distwp[p + j];
        }
#pragma unroll
        for (int j = 0; j < 4; ++j) {
            ushort2 u = *(const ushort2*)(hbb + (size_t)ss[j] * HIDD + tt);
            float f0 = b2f(u.x), f1 = b2f(u.y);
            float c0 = ee[j].x * r0 * ww[j], c1 = ee[j].y * r1 * ww[j];
            float c2 = ee[j].z * r2 * ww[j], c3 = ee[j].w * r3 * ww[j];
            a00 += c0 * f0; a01 += c0 * f1;
            a10 += c1 * f0; a11 += c1 * f1;
            a20 += c2 * f0; a21 += c2 * f1;
            a30 += c3 * f0; a31 += c3 * f1;
        }
    }
    for (; p < p1; ++p) {
        int s = srcp[p];
        float4 e = ((const float4*)exbuf)[p];
        float w = distwp[p];
        ushort2 u = *(const ushort2*)(hbb + (size_t)s * HIDD + tt);
        float f0 = b2f(u.x), f1 = b2f(u.y);
        float c0 = e.x * r0 * w, c1 = e.y * r1 * w, c2 = e.z * r2 * w, c3 = e.w * r3 * w;
        a00 += c0 * f0; a01 += c0 * f1;
        a10 += c1 * f0; a11 += c1 * f1;
        a20 += c2 * f0; a21 += c2 * f1;
        a30 += c3 * f0; a31 += c3 * f1;
    }
    b16* o = aggb + (size_t)n * 512;
    ushort2 w0; w0.x = f2b(a00); w0.y = f2b(a01); *(ushort2*)(o + tt) = w0;
    ushort2 w1; w1.x = f2b(a10); w1.y = f2b(a11); *(ushort2*)(o + 128 + tt) = w1;
    ushort2 w2; w2.x = f2b(a20); w2.y = f2b(a21); *(ushort2*)(o + 256 + tt) = w2;
    ushort2 w3; w3.x = f2b(a30); w3.y = f2b(a31); *(ushort2*)(o + 384 + tt) = w3;
}
// final: gather fp32 hL rows (36 wide), fuse norm + distw + mean + bias + lrelu
__global__ __launch_bounds__(64) void k_aggL(
    const int* __restrict__ rowptr, const int* __restrict__ srcp,
    const float* __restrict__ exbuf, const float* __restrict__ distwp,
    const float* __restrict__ hL, const float* __restrict__ bL, float* __restrict__ out) {
    __shared__ float sh[40];
    int n = blockIdx.x, t = threadIdx.x;
    int p0 = rowptr[n], p1 = rowptr[n + 1];
    float d0 = 0.f, d1 = 0.f, d2 = 0.f, d3 = 0.f;
    for (int p = p0; p < p1; ++p) {
        float4 e = ((const float4*)exbuf)[p];
        d0 += e.x; d1 += e.y; d2 += e.z; d3 += e.w;
    }
    if (t < 36) {
        int hh = t / 9;
        float rv = (hh == 0) ? 1.f / (d0 + 1e-16f)
                 : (hh == 1) ? 1.f / (d1 + 1e-16f)
                 : (hh == 2) ? 1.f / (d2 + 1e-16f)
                             : 1.f / (d3 + 1e-16f);
        float acc = 0.f;
        for (int p = p0; p < p1; ++p) {
            int s = srcp[p];
            float a = exbuf[p * 4 + hh] * rv * distwp[p];
            acc += a * hL[(size_t)s * 36 + t];
        }
        sh[t] = acc;
    }
    __syncthreads();
    if (t < 9) {
        float v = 0.25f * (sh[t] + sh[t + 9] + sh[t + 18] + sh[t + 27]) + bL[t];
        out[(size_t)n * 9 + t] = lrelu(v, 0.1f);
    }
}

// ---------------- batchnorm ----------------
__global__ __launch_bounds__(128) void k_bnstats(const float* __restrict__ x, float* __restrict__ sums) {
    int f = threadIdx.x;
    float s = 0.f, q = 0.f;
    for (int r = blockIdx.x; r < NN; r += gridDim.x) {
        float v = x[(size_t)r * HIDD + f];
        s += v;
        q += v * v;
    }
    atomicAdd(&sums[f], s);
    atomicAdd(&sums[128 + f], q);
}
__global__ void k_bnfinal(const float* __restrict__ sums, const float* __restrict__ gamma,
                          const float* __restrict__ beta, float* __restrict__ scale,
                          float* __restrict__ shift) {
    int f = threadIdx.x;
    float m = sums[f] * (1.f / NN);
    float v = sums[128 + f] * (1.f / NN) - m * m;
    float sc = gamma[f] * rsqrtf(v + 1e-5f);
    scale[f] = sc;
    shift[f] = beta[f] - m * sc;
}
// writes fp32 hb (scores/residual) + bf16 hbb (gather operand)
__global__ void k_bnapply(const float* __restrict__ x, const float* __restrict__ scale,
                          const float* __restrict__ shift, float* __restrict__ hb,
                          b16* __restrict__ hbb) {
    int i = blockIdx.x * blockDim.x + threadIdx.x;
    if (i >= NN * HIDD / 4) return;
    int c = i & 31;
    float4 v = ((const float4*)x)[i];
    float4 sc = ((const float4*)scale)[c];
    float4 sh = ((const float4*)shift)[c];
    float4 y;
    y.x = lrelu(v.x * sc.x + sh.x, 0.1f);
    y.y = lrelu(v.y * sc.y + sh.y, 0.1f);
    y.z = lrelu(v.z * sc.z + sh.z, 0.1f);
    y.w = lrelu(v.w * sc.w + sh.w, 0.1f);
    ((float4*)hb)[i] = y;
    ushort4 yb;
    yb.x = f2b(y.x); yb.y = f2b(y.y); yb.z = f2b(y.z); yb.w = f2b(y.w);
    ((ushort4*)hbb)[i] = yb;
}

// ---------------- final small GEMM: hL = hb @ WLcat  [N,36] ----------------
__global__ __launch_bounds__(64) void k_gemmL(const float* __restrict__ hb,
                                              const float* __restrict__ WL,
                                              float* __restrict__ hL) {
    __shared__ float row[128];
    int n = blockIdx.x, t = threadIdx.x;
    row[t] = hb[(size_t)n * HIDD + t];
    row[t + 64] = hb[(size_t)n * HIDD + t + 64];
    __syncthreads();
    if (t < 36) {
        int h = t / 9, c = t - h * 9;
        const float* w = WL + h * (HIDD * NCLS) + c;
        float acc = 0.f;
#pragma unroll 8
        for (int k = 0; k < HIDD; ++k) acc += row[k] * w[k * NCLS];
        hL[(size_t)n * 36 + t] = acc;
    }
}

extern "C" void kernel_launch(void* const* d_in, const int* in_sizes, int n_in,
                              void* d_out, int out_size, void* d_ws, size_t ws_size,
                              hipStream_t stream) {
    const float* x = (const float*)d_in[0];
    const int* ei = (const int*)d_in[1];
    const int* src = ei;
    const int* dst = ei + NE;
    const int* etype = (const int*)d_in[2];
    const int* edist = (const int*)d_in[3];
    const float* W0 = (const float*)d_in[4];
    const float* asrc0 = (const float*)d_in[5];
    const float* adst0 = (const float*)d_in[6];
    const float* aedge0 = (const float*)d_in[7];
    const float* b0 = (const float*)d_in[8];
    const float* rel0 = (const float*)d_in[9];
    const float* Wm = (const float*)d_in[10];
    const float* asrcm = (const float*)d_in[11];
    const float* adstm = (const float*)d_in[12];
    const float* aedgem = (const float*)d_in[13];
    const float* bm = (const float*)d_in[14];
    const float* relm = (const float*)d_in[15];
    const float* WL = (const float*)d_in[16];
    const float* asrcL = (const float*)d_in[17];
    const float* adstL = (const float*)d_in[18];
    const float* aedgeL = (const float*)d_in[19];
    const float* bL = (const float*)d_in[20];
    const float* relL = (const float*)d_in[21];
    const float* bng = (const float*)d_in[22];
    const float* bnb = (const float*)d_in[23];
    float* out = (float*)d_out;

    char* w = (char*)d_ws;
    size_t off = 0;
    auto alloc = [&](size_t bytes) -> char* {
        char* p = w + off;
        off = (off + bytes + 255) & ~(size_t)255;
        return p;
    };
    // region 0: xb (bf16 [NN][768]) during prep+conv0 GEMM; then xbuf/hb/hL
    char* ws0 = alloc((size_t)NN * FIN * 2);             // 30.72 MB
    b16* xb = (b16*)ws0;
    float* xbuf = (float*)ws0;                           // [NN][128] fp32 (10.24 MB)
    float* hb = (float*)(ws0 + 10240000);                // [NN][128] fp32
    float* hL = (float*)(ws0 + 20480000);                // [NN][36]  fp32
    b16* h0b = (b16*)alloc((size_t)NN * 512 * 2);        // h0 bf16 / agg bf16 (20.48 MB)
    b16* B0t = (b16*)alloc((size_t)512 * FIN * 2);
    b16* Bmt = (b16*)alloc((size_t)3 * HIDD * 512 * 2);
    b16* hbb = (b16*)alloc((size_t)NN * HIDD * 2);       // bf16 mirror of hb
    float* exbuf = (float*)alloc((size_t)NE * 4 * 4);    // exp(logits); aliased w/ eidx
    int* eidx = (int*)exbuf;
    float* es = (float*)alloc((size_t)NN * 4 * 4);
    float* ed = (float*)alloc((size_t)NN * 4 * 4);
    int* srcp = (int*)alloc((size_t)NE * 4);
    int* dstpp = (int*)alloc((size_t)NE * 4);
    int* etpp = (int*)alloc((size_t)NE * 4);
    float* distwp = (float*)alloc((size_t)NE * 4);
    float* bnsums = (float*)alloc(256 * 4);
    float* scale = (float*)alloc(128 * 4);
    float* shift = (float*)alloc(128 * 4);
    float* wsmb = (float*)alloc(1536 * 4);
    float* wdmb = (float*)alloc(1536 * 4);
    float* etab = (float*)alloc(800 * 4);
    int* counts = (int*)alloc((size_t)NN * 4);
    int* rowptr = (int*)alloc((size_t)(NN + 1) * 4);
    int* cursor = (int*)alloc((size_t)NN * 4);

    const int B256 = 256;
    int gNE = (NE + 255) / 256;
    int gNN = (NN + 255) / 256;

    // CSR + permutation (once, reused by all 5 convs)
    k_zero<<<gNN, B256, 0, stream>>>((float*)counts, NN);
    k_count<<<gNE, B256, 0, stream>>>(dst, counts);
    k_scan<<<1, 1024, 0, stream>>>(counts, rowptr);
    k_copy_i32<<<gNN, B256, 0, stream>>>(cursor, rowptr, NN);
    k_fill<<<gNE, B256, 0, stream>>>(dst, cursor, eidx);
    k_permute<<<gNE, B256, 0, stream>>>(eidx, src, dst, etype, edist, srcp, dstpp, etpp, distwp);

    // small tables + weight conversions
    k_etab<<<4, B256, 0, stream>>>(rel0, relm, relL, aedge0, aedgem, aedgeL, etab);
    k_wsm<<<12, B256, 0, stream>>>(Wm, asrcm, adstm, wsmb, wdmb);
    k_cast_bf16<<<(NN * FIN / 4 + 255) / 256, B256, 0, stream>>>(x, xb, NN * FIN / 4);
    k_convB0<<<(512 * FIN + 255) / 256, B256, 0, stream>>>(W0, B0t);
    k_convBm<<<(3 * HIDD * 512 + 255) / 256, B256, 0, stream>>>(Wm, Bmt);

    int mblk = (NN + 127) / 128;  // 157

    // ---- conv0: transform-first, bf16 MFMA ----
    {
        dim3 g(mblk, 4);
        k_mfma_gemm<<<g, 256, 0, stream>>>(xb, B0t, NN, FIN, 512, 1.f, h0b, nullptr, nullptr, nullptr);
        k_scores_b<<<NN, 128, 0, stream>>>(h0b, asrc0, adst0, es, ed);
        k_edge1<<<gNE, B256, 0, stream>>>(srcp, dstpp, etpp, es, ed, etab + 0, exbuf);
        k_agg0<<<NN, 64, 0, stream>>>(rowptr, srcp, exbuf, distwp, h0b, b0, xbuf);
    }

    // ---- 3 middle convs: aggregate-first, bf16 MFMA ----
    for (int i = 0; i < 3; ++i) {
        k_zero<<<1, 256, 0, stream>>>(bnsums, 256);
        k_bnstats<<<200, 128, 0, stream>>>(xbuf, bnsums);
        k_bnfinal<<<1, 128, 0, stream>>>(bnsums, bng + i * 128, bnb + i * 128, scale, shift);
        k_bnapply<<<(NN * HIDD / 4 + 255) / 256, B256, 0, stream>>>(xbuf, scale, shift, hb, hbb);
        k_scores_f<<<NN, 128, 0, stream>>>(hb, wsmb + i * 512, wdmb + i * 512, es, ed);
        k_edge1<<<gNE, B256, 0, stream>>>(srcp, dstpp, etpp, es, ed, etab + (1 + i) * 160, exbuf);
        k_aggmid<<<NN, 64, 0, stream>>>(rowptr, srcp, exbuf, distwp, hbb, h0b);
        dim3 g(mblk, 1);
        k_mfma_gemm<<<g, 256, 0, stream>>>(h0b, Bmt + (size_t)i * HIDD * 512, NN, 512, HIDD, 0.25f,
                                           nullptr, xbuf, bm + i * 128, hb);
    }

    // ---- final conv: transform-first (36-wide), fp32 ----
    {
        k_zero<<<1, 256, 0, stream>>>(bnsums, 256);
        k_bnstats<<<200, 128, 0, stream>>>(xbuf, bnsums);
        k_bnfinal<<<1, 128, 0, stream>>>(bnsums, bng + 3 * 128, bnb + 3 * 128, scale, shift);
        k_bnapply<<<(NN * HIDD / 4 + 255) / 256, B256, 0, stream>>>(xbuf, scale, shift, hb, hbb);
        k_gemmL<<<NN, 64, 0, stream>>>(hb, WL, hL);
        k_scoresL<<<gNN, B256, 0, stream>>>(hL, asrcL, adstL, es, ed);
        k_edge1<<<gNE, B256, 0, stream>>>(srcp, dstpp, etpp, es, ed, etab + 4 * 160, exbuf);
        k_aggL<<<NN, 64, 0, stream>>>(rowptr, srcp, exbuf, distwp, hL, bL, out);
    }
}

// Round 3
// 663.092 us; speedup vs baseline: 2.2658x; 1.1345x over previous
//
#include <hip/hip_runtime.h>
#include <math.h>

#define NN   20000
#define NE   320000
#define NH   4
#define NREL 40
#define FIN  768
#define HIDD 128
#define NCLS 9
#define MAXDEG 128

typedef __attribute__((ext_vector_type(8))) short short8;
typedef __attribute__((ext_vector_type(4))) float f32x4;
typedef unsigned short b16;

__device__ __forceinline__ float lrelu(float v, float s) { return v > 0.f ? v : v * s; }
__device__ __forceinline__ b16 f2b(float f) {
    unsigned int u = __float_as_uint(f);
    unsigned int r = u + 0x7FFFu + ((u >> 16) & 1u);
    return (b16)(r >> 16);
}
__device__ __forceinline__ float b2f(b16 u) { return __uint_as_float(((unsigned int)u) << 16); }

// ---------------- utility ----------------
__global__ void k_zero(float* p, int n) {
    int i = blockIdx.x * blockDim.x + threadIdx.x;
    if (i < n) p[i] = 0.f;
}
__global__ void k_copy_i32(int* d, const int* s, int n) {
    int i = blockIdx.x * blockDim.x + threadIdx.x;
    if (i < n) d[i] = s[i];
}

// ---------------- CSR build ----------------
__global__ void k_count(const int* __restrict__ dst, int* __restrict__ counts) {
    int e = blockIdx.x * blockDim.x + threadIdx.x;
    if (e < NE) atomicAdd(&counts[dst[e]], 1);
}
__global__ void k_scan(const int* __restrict__ counts, int* __restrict__ rowptr) {
    __shared__ int sh[1024];
    int t = threadIdx.x;
    int base = t * 20;
    int sum = 0;
    if (t < 1000) for (int k = 0; k < 20; ++k) sum += counts[base + k];
    sh[t] = sum;
    __syncthreads();
    for (int off = 1; off < 1024; off <<= 1) {
        int v = (t >= off) ? sh[t - off] : 0;
        __syncthreads();
        sh[t] += v;
        __syncthreads();
    }
    int ex = (t == 0) ? 0 : sh[t - 1];
    if (t == 0) rowptr[0] = 0;
    if (t < 1000) {
        int run = ex;
        for (int k = 0; k < 20; ++k) {
            run += counts[base + k];
            rowptr[base + k + 1] = run;
        }
    }
}
__global__ void k_fill(const int* __restrict__ dst, int* __restrict__ cursor, int* __restrict__ eidx) {
    int e = blockIdx.x * blockDim.x + threadIdx.x;
    if (e < NE) {
        int pos = atomicAdd(&cursor[dst[e]], 1);
        eidx[pos] = e;
    }
}
__global__ void k_permute(const int* __restrict__ eidx, const int* __restrict__ src,
                          const int* __restrict__ etype, const int* __restrict__ dist,
                          int* __restrict__ srcp, int* __restrict__ etp,
                          float* __restrict__ distwp) {
    int p = blockIdx.x * blockDim.x + threadIdx.x;
    if (p >= NE) return;
    int e = eidx[p];
    srcp[p] = src[e];
    etp[p] = etype[e];
    distwp[p] = 1.f / (1.f + (float)dist[e]);
}

// ---------------- small tables ----------------
__global__ void k_etab(const float* __restrict__ rel0, const float* __restrict__ relm,
                       const float* __restrict__ relL, const float* __restrict__ ae0,
                       const float* __restrict__ aem, const float* __restrict__ aeL,
                       float* __restrict__ etab) {
    int id = blockIdx.x * blockDim.x + threadIdx.x;
    if (id >= 5 * NREL * NH) return;
    int tab = id / (NREL * NH);
    int rem = id % (NREL * NH);
    int t = rem >> 2, h = rem & 3;
    const float *rel, *ae;
    if (tab == 0)      { rel = rel0;                        ae = ae0; }
    else if (tab <= 3) { rel = relm + (tab - 1) * NREL * 2; ae = aem + (tab - 1) * NH * 2; }
    else               { rel = relL;                        ae = aeL; }
    etab[id] = rel[t * 2] * ae[h * 2] + rel[t * 2 + 1] * ae[h * 2 + 1];
}
__global__ void k_wsm(const float* __restrict__ Wm, const float* __restrict__ asrcm,
                      const float* __restrict__ adstm, float* __restrict__ wsm,
                      float* __restrict__ wdm) {
    int id = blockIdx.x * blockDim.x + threadIdx.x;
    if (id >= 2 * 3 * NH * HIDD) return;
    int which = id / (3 * NH * HIDD);
    int r = id % (3 * NH * HIDD);
    int ih = r / HIDD;
    int f = r % HIDD;
    const float* w = Wm + ((size_t)ih * HIDD + f) * HIDD;
    const float* a = (which ? adstm : asrcm) + ih * HIDD;
    float acc = 0.f;
    for (int o = 0; o < HIDD; ++o) acc += w[o] * a[o];
    (which ? wdm : wsm)[r] = acc;
}

// ---------------- bf16 conversions ----------------
__global__ void k_cast_bf16(const float* __restrict__ in, b16* __restrict__ out, int n4) {
    int i = blockIdx.x * blockDim.x + threadIdx.x;
    if (i >= n4) return;
    float4 v = ((const float4*)in)[i];
    ushort4 o;
    o.x = f2b(v.x); o.y = f2b(v.y); o.z = f2b(v.z); o.w = f2b(v.w);
    ((ushort4*)out)[i] = o;
}
__global__ void k_convB0(const float* __restrict__ W0, b16* __restrict__ B0t) {
    int id = blockIdx.x * blockDim.x + threadIdx.x;
    if (id >= 512 * FIN) return;
    int c = id / FIN, k = id % FIN;
    int h = c >> 7, o = c & 127;
    B0t[id] = f2b(W0[((size_t)h * FIN + k) * HIDD + o]);
}
__global__ void k_convBm(const float* __restrict__ Wm, b16* __restrict__ Bmt) {
    int id = blockIdx.x * blockDim.x + threadIdx.x;
    if (id >= 3 * HIDD * 512) return;
    int i = id / (HIDD * 512);
    int r = id % (HIDD * 512);
    int o = r / 512, hf = r % 512;
    Bmt[id] = f2b(Wm[(size_t)i * 512 * HIDD + (size_t)hf * HIDD + o]);
}
// WLt[48][128], cf = h*9+c (zero-pad 36..47): WLt[cf][k] = WL[h][k][c]
__global__ void k_convBL(const float* __restrict__ WL, b16* __restrict__ WLt) {
    int id = blockIdx.x * blockDim.x + threadIdx.x;
    if (id >= 48 * HIDD) return;
    int cf = id / HIDD, k = id % HIDD;
    float v = 0.f;
    if (cf < 36) {
        int h = cf / 9, c = cf % 9;
        v = WL[((size_t)h * HIDD + k) * NCLS + c];
    }
    WLt[id] = f2b(v);
}

// ---------------- MFMA bf16 GEMM: C = A[M,K] @ Bt[N,K]^T ----------------
// 128x128 tile, 4 waves. Epilogue: Cb -> bf16; else fp32 scl*acc+bias+resid.
// If esp: also fused attention scores for head = blockIdx.y (col-block == head).
__global__ __launch_bounds__(256) void k_mfma_gemm(
    const b16* __restrict__ A, const b16* __restrict__ Bt, int M, int K, int N,
    float scl, b16* __restrict__ Cb, float* __restrict__ Cf,
    const float* __restrict__ bias, const float* __restrict__ resid,
    const float* __restrict__ asv, const float* __restrict__ adv,
    float* __restrict__ esp, float* __restrict__ edp) {
    __shared__ b16 As[128][40];
    __shared__ b16 Bs[128][40];
    __shared__ float sc_es[2][128];
    __shared__ float sc_ed[2][128];
    int tid = threadIdx.x;
    int lane = tid & 63, wave = tid >> 6;
    int wm = wave >> 1, wn = wave & 1;
    int l16 = lane & 15, quad = lane >> 4;
    int row0 = blockIdx.x * 128, col0 = blockIdx.y * 128;

    int c0 = tid, c1 = tid + 256;
    int ar0 = c0 >> 2, as0 = (c0 & 3) << 3;
    int ar1 = c1 >> 2, as1 = (c1 & 3) << 3;
    bool va0 = (row0 + ar0) < M, va1 = (row0 + ar1) < M;
    const b16* Ap0 = A + (size_t)(row0 + ar0) * K + as0;
    const b16* Ap1 = A + (size_t)(row0 + ar1) * K + as1;
    const b16* Bp0 = Bt + (size_t)(col0 + ar0) * K + as0;
    const b16* Bp1 = Bt + (size_t)(col0 + ar1) * K + as1;

    f32x4 acc[4][4];
#pragma unroll
    for (int i = 0; i < 4; ++i)
#pragma unroll
        for (int j = 0; j < 4; ++j) acc[i][j] = (f32x4){0.f, 0.f, 0.f, 0.f};
    short8 zz = {0, 0, 0, 0, 0, 0, 0, 0};

    for (int kt = 0; kt < K; kt += 32) {
        short8 a0 = va0 ? *(const short8*)(Ap0 + kt) : zz;
        short8 a1 = va1 ? *(const short8*)(Ap1 + kt) : zz;
        short8 b0 = *(const short8*)(Bp0 + kt);
        short8 b1 = *(const short8*)(Bp1 + kt);
        __syncthreads();
        *(short8*)&As[ar0][as0] = a0;
        *(short8*)&As[ar1][as1] = a1;
        *(short8*)&Bs[ar0][as0] = b0;
        *(short8*)&Bs[ar1][as1] = b1;
        __syncthreads();
        short8 bf[4];
#pragma unroll
        for (int ni = 0; ni < 4; ++ni)
            bf[ni] = *(const short8*)&Bs[wn * 64 + ni * 16 + l16][quad * 8];
#pragma unroll
        for (int mi = 0; mi < 4; ++mi) {
            short8 af = *(const short8*)&As[wm * 64 + mi * 16 + l16][quad * 8];
#pragma unroll
            for (int ni = 0; ni < 4; ++ni)
                acc[mi][ni] = __builtin_amdgcn_mfma_f32_16x16x32_bf16(af, bf[ni], acc[mi][ni], 0, 0, 0);
        }
    }
    if (Cb) {
#pragma unroll
        for (int mi = 0; mi < 4; ++mi) {
            int rb = row0 + wm * 64 + mi * 16 + quad * 4;
#pragma unroll
            for (int ni = 0; ni < 4; ++ni) {
                int c = col0 + wn * 64 + ni * 16 + l16;
#pragma unroll
                for (int r = 0; r < 4; ++r) {
                    int row = rb + r;
                    if (row < M) Cb[(size_t)row * N + c] = f2b(acc[mi][ni][r]);
                }
            }
        }
    } else {
#pragma unroll
        for (int mi = 0; mi < 4; ++mi) {
            int rb = row0 + wm * 64 + mi * 16 + quad * 4;
#pragma unroll
            for (int ni = 0; ni < 4; ++ni) {
                int c = col0 + wn * 64 + ni * 16 + l16;
#pragma unroll
                for (int r = 0; r < 4; ++r) {
                    int row = rb + r;
                    if (row < M) {
                        float v = acc[mi][ni][r] * scl + bias[c] + resid[(size_t)row * N + c];
                        Cf[(size_t)row * N + c] = v;
                    }
                }
            }
        }
    }
    if (esp) {
        int h = blockIdx.y;
        float as_c[4], ad_c[4];
#pragma unroll
        for (int ni = 0; ni < 4; ++ni) {
            int c = wn * 64 + ni * 16 + l16;
            as_c[ni] = asv[h * 128 + c];
            ad_c[ni] = adv[h * 128 + c];
        }
#pragma unroll
        for (int mi = 0; mi < 4; ++mi) {
#pragma unroll
            for (int r = 0; r < 4; ++r) {
                float pes = 0.f, ped = 0.f;
#pragma unroll
                for (int ni = 0; ni < 4; ++ni) {
                    float v = acc[mi][ni][r];
                    pes += v * as_c[ni];
                    ped += v * ad_c[ni];
                }
#pragma unroll
                for (int m = 1; m < 16; m <<= 1) {
                    pes += __shfl_xor(pes, m, 64);
                    ped += __shfl_xor(ped, m, 64);
                }
                if (l16 == 0) {
                    int rl = wm * 64 + mi * 16 + quad * 4 + r;
                    sc_es[wn][rl] = pes;
                    sc_ed[wn][rl] = ped;
                }
            }
        }
        __syncthreads();
        if (tid < 128) {
            int row = row0 + tid;
            if (row < M) {
                esp[row * 4 + h] = sc_es[0][tid] + sc_es[1][tid];
                edp[row * 4 + h] = sc_ed[0][tid] + sc_ed[1][tid];
            }
        }
    }
}

// ---------------- gemmL: hL[N,36] = hbb[N,128] @ WLt^T via MFMA ----------------
__global__ __launch_bounds__(256) void k_gemmL_mfma(
    const b16* __restrict__ hbb, const b16* __restrict__ WLt, float* __restrict__ hL) {
    int tid = threadIdx.x;
    int lane = tid & 63, wave = tid >> 6;
    int l16 = lane & 15, quad = lane >> 4;
    int base = blockIdx.x * 64 + wave * 16;
    int na = base + l16;
    f32x4 acc[3];
#pragma unroll
    for (int ct = 0; ct < 3; ++ct) acc[ct] = (f32x4){0.f, 0.f, 0.f, 0.f};
    short8 zz = {0, 0, 0, 0, 0, 0, 0, 0};
#pragma unroll
    for (int k0 = 0; k0 < 128; k0 += 32) {
        short8 af = (na < NN) ? *(const short8*)(hbb + (size_t)na * HIDD + k0 + quad * 8) : zz;
#pragma unroll
        for (int ct = 0; ct < 3; ++ct) {
            short8 bf = *(const short8*)(WLt + (size_t)(ct * 16 + l16) * HIDD + k0 + quad * 8);
            acc[ct] = __builtin_amdgcn_mfma_f32_16x16x32_bf16(af, bf, acc[ct], 0, 0, 0);
        }
    }
#pragma unroll
    for (int ct = 0; ct < 3; ++ct) {
        int col = ct * 16 + l16;
        if (col < 36) {
#pragma unroll
            for (int r = 0; r < 4; ++r) {
                int row = base + quad * 4 + r;
                if (row < NN) hL[(size_t)row * 36 + col] = acc[ct][r];
            }
        }
    }
}

// ---------------- scoresL ----------------
__global__ void k_scoresL(const float* __restrict__ hL, const float* __restrict__ aS,
                          const float* __restrict__ aD, float* __restrict__ es,
                          float* __restrict__ ed) {
    int n = blockIdx.x * blockDim.x + threadIdx.x;
    if (n >= NN) return;
    for (int h = 0; h < NH; ++h) {
        float s = 0.f, d = 0.f;
        for (int c = 0; c < NCLS; ++c) {
            float v = hL[(size_t)n * 36 + h * 9 + c];
            s += v * aS[h * 9 + c];
            d += v * aD[h * 9 + c];
        }
        es[n * 4 + h] = s;
        ed[n * 4 + h] = d;
    }
}

// ---------------- fused edge-softmax + aggregation ----------------
// pass1: per-edge exp(lrelu(logit))*distw -> LDS, den reduced in-wave.
// conv0 variant: gather bf16 h0 rows (512-wide), fuse mean+bias.
__global__ __launch_bounds__(64) void k_agg0_f(
    const int* __restrict__ rowptr, const int* __restrict__ srcp,
    const int* __restrict__ etpp, const float* __restrict__ distwp,
    const float* __restrict__ es, const float* __restrict__ ed,
    const float* __restrict__ etab, const b16* __restrict__ h0b,
    const float* __restrict__ b0, float* __restrict__ xout) {
    __shared__ float4 exw[MAXDEG];
    int n = blockIdx.x, t = threadIdx.x;
    int p0 = rowptr[n], p1 = rowptr[n + 1];
    int deg = p1 - p0;
    float4 edn = ((const float4*)ed)[n];
    float d0 = 0.f, d1 = 0.f, d2 = 0.f, d3 = 0.f;
    for (int p = p0 + t; p < p1; p += 64) {
        int s = srcp[p], ty = etpp[p];
        float w = distwp[p];
        float4 a = ((const float4*)es)[s];
        float4 c = ((const float4*)etab)[ty];
        float e0 = __expf(lrelu(a.x + edn.x + c.x, 0.2f));
        float e1 = __expf(lrelu(a.y + edn.y + c.y, 0.2f));
        float e2 = __expf(lrelu(a.z + edn.z + c.z, 0.2f));
        float e3 = __expf(lrelu(a.w + edn.w + c.w, 0.2f));
        d0 += e0; d1 += e1; d2 += e2; d3 += e3;
        int ix = p - p0;
        if (ix < MAXDEG) exw[ix] = make_float4(e0 * w, e1 * w, e2 * w, e3 * w);
    }
#pragma unroll
    for (int off = 32; off > 0; off >>= 1) {
        d0 += __shfl_down(d0, off, 64);
        d1 += __shfl_down(d1, off, 64);
        d2 += __shfl_down(d2, off, 64);
        d3 += __shfl_down(d3, off, 64);
    }
    d0 = __shfl(d0, 0, 64); d1 = __shfl(d1, 0, 64);
    d2 = __shfl(d2, 0, 64); d3 = __shfl(d3, 0, 64);
    float r0 = 1.f / (d0 + 1e-16f), r1 = 1.f / (d1 + 1e-16f);
    float r2 = 1.f / (d2 + 1e-16f), r3 = 1.f / (d3 + 1e-16f);
    __syncthreads();
    float acc0 = 0.f, acc1 = 0.f;
    int tt = t * 2;
    if (deg <= MAXDEG) {
        int p = p0;
        for (; p + 4 <= p1; p += 4) {
            int ib = p - p0;
            int ss[4]; float4 ee[4];
#pragma unroll
            for (int j = 0; j < 4; ++j) { ss[j] = srcp[p + j]; ee[j] = exw[ib + j]; }
#pragma unroll
            for (int j = 0; j < 4; ++j) {
                const b16* hr = h0b + (size_t)ss[j] * 512;
                ushort2 u0 = *(const ushort2*)(hr + tt);
                ushort2 u1 = *(const ushort2*)(hr + 128 + tt);
                ushort2 u2 = *(const ushort2*)(hr + 256 + tt);
                ushort2 u3 = *(const ushort2*)(hr + 384 + tt);
                float c0 = ee[j].x * r0, c1 = ee[j].y * r1;
                float c2 = ee[j].z * r2, c3 = ee[j].w * r3;
                acc0 += c0 * b2f(u0.x) + c1 * b2f(u1.x) + c2 * b2f(u2.x) + c3 * b2f(u3.x);
                acc1 += c0 * b2f(u0.y) + c1 * b2f(u1.y) + c2 * b2f(u2.y) + c3 * b2f(u3.y);
            }
        }
        for (; p < p1; ++p) {
            int s = srcp[p];
            float4 e = exw[p - p0];
            const b16* hr = h0b + (size_t)s * 512;
            ushort2 u0 = *(const ushort2*)(hr + tt);
            ushort2 u1 = *(const ushort2*)(hr + 128 + tt);
            ushort2 u2 = *(const ushort2*)(hr + 256 + tt);
            ushort2 u3 = *(const ushort2*)(hr + 384 + tt);
            float c0 = e.x * r0, c1 = e.y * r1, c2 = e.z * r2, c3 = e.w * r3;
            acc0 += c0 * b2f(u0.x) + c1 * b2f(u1.x) + c2 * b2f(u2.x) + c3 * b2f(u3.x);
            acc1 += c0 * b2f(u0.y) + c1 * b2f(u1.y) + c2 * b2f(u2.y) + c3 * b2f(u3.y);
        }
    } else {
        for (int p = p0; p < p1; ++p) {
            int s = srcp[p];
            int ix = p - p0;
            float4 e;
            if (ix < MAXDEG) e = exw[ix];
            else {
                int ty = etpp[p];
                float w = distwp[p];
                float4 a = ((const float4*)es)[s];
                float4 c = ((const float4*)etab)[ty];
                e.x = __expf(lrelu(a.x + edn.x + c.x, 0.2f)) * w;
                e.y = __expf(lrelu(a.y + edn.y + c.y, 0.2f)) * w;
                e.z = __expf(lrelu(a.z + edn.z + c.z, 0.2f)) * w;
                e.w = __expf(lrelu(a.w + edn.w + c.w, 0.2f)) * w;
            }
            const b16* hr = h0b + (size_t)s * 512;
            ushort2 u0 = *(const ushort2*)(hr + tt);
            ushort2 u1 = *(const ushort2*)(hr + 128 + tt);
            ushort2 u2 = *(const ushort2*)(hr + 256 + tt);
            ushort2 u3 = *(const ushort2*)(hr + 384 + tt);
            float c0 = e.x * r0, c1 = e.y * r1, c2 = e.z * r2, c3 = e.w * r3;
            acc0 += c0 * b2f(u0.x) + c1 * b2f(u1.x) + c2 * b2f(u2.x) + c3 * b2f(u3.x);
            acc1 += c0 * b2f(u0.y) + c1 * b2f(u1.y) + c2 * b2f(u2.y) + c3 * b2f(u3.y);
        }
    }
    xout[(size_t)n * HIDD + tt] = 0.25f * acc0 + b0[tt];
    xout[(size_t)n * HIDD + tt + 1] = 0.25f * acc1 + b0[tt + 1];
}
// mid variant: gather bf16 hb rows (128-wide), write bf16 agg [N][512]
__global__ __launch_bounds__(64) void k_aggmid_f(
    const int* __restrict__ rowptr, const int* __restrict__ srcp,
    const int* __restrict__ etpp, const float* __restrict__ distwp,
    const float* __restrict__ es, const float* __restrict__ ed,
    const float* __restrict__ etab, const b16* __restrict__ hbb,
    b16* __restrict__ aggb) {
    __shared__ float4 exw[MAXDEG];
    int n = blockIdx.x, t = threadIdx.x;
    int p0 = rowptr[n], p1 = rowptr[n + 1];
    int deg = p1 - p0;
    float4 edn = ((const float4*)ed)[n];
    float d0 = 0.f, d1 = 0.f, d2 = 0.f, d3 = 0.f;
    for (int p = p0 + t; p < p1; p += 64) {
        int s = srcp[p], ty = etpp[p];
        float w = distwp[p];
        float4 a = ((const float4*)es)[s];
        float4 c = ((const float4*)etab)[ty];
        float e0 = __expf(lrelu(a.x + edn.x + c.x, 0.2f));
        float e1 = __expf(lrelu(a.y + edn.y + c.y, 0.2f));
        float e2 = __expf(lrelu(a.z + edn.z + c.z, 0.2f));
        float e3 = __expf(lrelu(a.w + edn.w + c.w, 0.2f));
        d0 += e0; d1 += e1; d2 += e2; d3 += e3;
        int ix = p - p0;
        if (ix < MAXDEG) exw[ix] = make_float4(e0 * w, e1 * w, e2 * w, e3 * w);
    }
#pragma unroll
    for (int off = 32; off > 0; off >>= 1) {
        d0 += __shfl_down(d0, off, 64);
        d1 += __shfl_down(d1, off, 64);
        d2 += __shfl_down(d2, off, 64);
        d3 += __shfl_down(d3, off, 64);
    }
    d0 = __shfl(d0, 0, 64); d1 = __shfl(d1, 0, 64);
    d2 = __shfl(d2, 0, 64); d3 = __shfl(d3, 0, 64);
    float r0 = 1.f / (d0 + 1e-16f), r1 = 1.f / (d1 + 1e-16f);
    float r2 = 1.f / (d2 + 1e-16f), r3 = 1.f / (d3 + 1e-16f);
    __syncthreads();
    float a00 = 0.f, a01 = 0.f, a10 = 0.f, a11 = 0.f;
    float a20 = 0.f, a21 = 0.f, a30 = 0.f, a31 = 0.f;
    int tt = t * 2;
    if (deg <= MAXDEG) {
        int p = p0;
        for (; p + 4 <= p1; p += 4) {
            int ib = p - p0;
            int ss[4]; float4 ee[4];
#pragma unroll
            for (int j = 0; j < 4; ++j) { ss[j] = srcp[p + j]; ee[j] = exw[ib + j]; }
#pragma unroll
            for (int j = 0; j < 4; ++j) {
                ushort2 u = *(const ushort2*)(hbb + (size_t)ss[j] * HIDD + tt);
                float f0 = b2f(u.x), f1 = b2f(u.y);
                float c0 = ee[j].x * r0, c1 = ee[j].y * r1;
                float c2 = ee[j].z * r2, c3 = ee[j].w * r3;
                a00 += c0 * f0; a01 += c0 * f1;
                a10 += c1 * f0; a11 += c1 * f1;
                a20 += c2 * f0; a21 += c2 * f1;
                a30 += c3 * f0; a31 += c3 * f1;
            }
        }
        for (; p < p1; ++p) {
            int s = srcp[p];
            float4 e = exw[p - p0];
            ushort2 u = *(const ushort2*)(hbb + (size_t)s * HIDD + tt);
            float f0 = b2f(u.x), f1 = b2f(u.y);
            float c0 = e.x * r0, c1 = e.y * r1, c2 = e.z * r2, c3 = e.w * r3;
            a00 += c0 * f0; a01 += c0 * f1;
            a10 += c1 * f0; a11 += c1 * f1;
            a20 += c2 * f0; a21 += c2 * f1;
            a30 += c3 * f0; a31 += c3 * f1;
        }
    } else {
        for (int p = p0; p < p1; ++p) {
            int s = srcp[p];
            int ix = p - p0;
            float4 e;
            if (ix < MAXDEG) e = exw[ix];
            else {
                int ty = etpp[p];
                float w = distwp[p];
                float4 a = ((const float4*)es)[s];
                float4 c = ((const float4*)etab)[ty];
                e.x = __expf(lrelu(a.x + edn.x + c.x, 0.2f)) * w;
                e.y = __expf(lrelu(a.y + edn.y + c.y, 0.2f)) * w;
                e.z = __expf(lrelu(a.z + edn.z + c.z, 0.2f)) * w;
                e.w = __expf(lrelu(a.w + edn.w + c.w, 0.2f)) * w;
            }
            ushort2 u = *(const ushort2*)(hbb + (size_t)s * HIDD + tt);
            float f0 = b2f(u.x), f1 = b2f(u.y);
            float c0 = e.x * r0, c1 = e.y * r1, c2 = e.z * r2, c3 = e.w * r3;
            a00 += c0 * f0; a01 += c0 * f1;
            a10 += c1 * f0; a11 += c1 * f1;
            a20 += c2 * f0; a21 += c2 * f1;
            a30 += c3 * f0; a31 += c3 * f1;
        }
    }
    b16* o = aggb + (size_t)n * 512;
    ushort2 w0; w0.x = f2b(a00); w0.y = f2b(a01); *(ushort2*)(o + tt) = w0;
    ushort2 w1; w1.x = f2b(a10); w1.y = f2b(a11); *(ushort2*)(o + 128 + tt) = w1;
    ushort2 w2; w2.x = f2b(a20); w2.y = f2b(a21); *(ushort2*)(o + 256 + tt) = w2;
    ushort2 w3; w3.x = f2b(a30); w3.y = f2b(a31); *(ushort2*)(o + 384 + tt) = w3;
}
// final variant: gather fp32 hL rows (36-wide), fuse mean+bias+lrelu
__global__ __launch_bounds__(64) void k_aggL_f(
    const int* __restrict__ rowptr, const int* __restrict__ srcp,
    const int* __restrict__ etpp, const float* __restrict__ distwp,
    const float* __restrict__ es, const float* __restrict__ ed,
    const float* __restrict__ etab, const float* __restrict__ hL,
    const float* __restrict__ bL, float* __restrict__ out) {
    __shared__ float4 exw[MAXDEG];
    __shared__ float sh[40];
    int n = blockIdx.x, t = threadIdx.x;
    int p0 = rowptr[n], p1 = rowptr[n + 1];
    float4 edn = ((const float4*)ed)[n];
    float d0 = 0.f, d1 = 0.f, d2 = 0.f, d3 = 0.f;
    for (int p = p0 + t; p < p1; p += 64) {
        int s = srcp[p], ty = etpp[p];
        float w = distwp[p];
        float4 a = ((const float4*)es)[s];
        float4 c = ((const float4*)etab)[ty];
        float e0 = __expf(lrelu(a.x + edn.x + c.x, 0.2f));
        float e1 = __expf(lrelu(a.y + edn.y + c.y, 0.2f));
        float e2 = __expf(lrelu(a.z + edn.z + c.z, 0.2f));
        float e3 = __expf(lrelu(a.w + edn.w + c.w, 0.2f));
        d0 += e0; d1 += e1; d2 += e2; d3 += e3;
        int ix = p - p0;
        if (ix < MAXDEG) exw[ix] = make_float4(e0 * w, e1 * w, e2 * w, e3 * w);
    }
#pragma unroll
    for (int off = 32; off > 0; off >>= 1) {
        d0 += __shfl_down(d0, off, 64);
        d1 += __shfl_down(d1, off, 64);
        d2 += __shfl_down(d2, off, 64);
        d3 += __shfl_down(d3, off, 64);
    }
    d0 = __shfl(d0, 0, 64); d1 = __shfl(d1, 0, 64);
    d2 = __shfl(d2, 0, 64); d3 = __shfl(d3, 0, 64);
    __syncthreads();
    if (t < 36) {
        int hh = t / 9;
        float rv = (hh == 0) ? 1.f / (d0 + 1e-16f)
                 : (hh == 1) ? 1.f / (d1 + 1e-16f)
                 : (hh == 2) ? 1.f / (d2 + 1e-16f)
                             : 1.f / (d3 + 1e-16f);
        float acc = 0.f;
        for (int p = p0; p < p1; ++p) {
            int s = srcp[p];
            int ix = p - p0;
            float av;
            if (ix < MAXDEG) {
                float4 e = exw[ix];
                av = (hh == 0) ? e.x : (hh == 1) ? e.y : (hh == 2) ? e.z : e.w;
            } else {
                int ty = etpp[p];
                float w = distwp[p];
                float a4 = ((const float4*)es)[s].x;  // recompute per-head
                float4 a = ((const float4*)es)[s];
                float4 c = ((const float4*)etab)[ty];
                float lv = (hh == 0) ? a.x + edn.x + c.x
                         : (hh == 1) ? a.y + edn.y + c.y
                         : (hh == 2) ? a.z + edn.z + c.z
                                     : a.w + edn.w + c.w;
                av = __expf(lrelu(lv, 0.2f)) * w;
                (void)a4;
            }
            acc += av * rv * hL[(size_t)s * 36 + t];
        }
        sh[t] = acc;
    }
    __syncthreads();
    if (t < 9) {
        float v = 0.25f * (sh[t] + sh[t + 9] + sh[t + 18] + sh[t + 27]) + bL[t];
        out[(size_t)n * 9 + t] = lrelu(v, 0.1f);
    }
}

// ---------------- batchnorm (atomic-free partials) ----------------
__global__ __launch_bounds__(128) void k_bnstats(const float* __restrict__ x, float* __restrict__ partial) {
    int f = threadIdx.x;
    float s = 0.f, q = 0.f;
    for (int r = blockIdx.x; r < NN; r += gridDim.x) {
        float v = x[(size_t)r * HIDD + f];
        s += v;
        q += v * v;
    }
    partial[blockIdx.x * 256 + f] = s;
    partial[blockIdx.x * 256 + 128 + f] = q;
}
__global__ void k_bnfinal(const float* __restrict__ partial, const float* __restrict__ gamma,
                          const float* __restrict__ beta, float* __restrict__ scale,
                          float* __restrict__ shift) {
    int f = threadIdx.x;
    float s = 0.f, q = 0.f;
    for (int j = 0; j < 200; ++j) {
        s += partial[j * 256 + f];
        q += partial[j * 256 + 128 + f];
    }
    float m = s * (1.f / NN);
    float v = q * (1.f / NN) - m * m;
    float sc = gamma[f] * rsqrtf(v + 1e-5f);
    scale[f] = sc;
    shift[f] = beta[f] - m * sc;
}
// fused BN-apply + (optional) mid-layer scores; one 64-thread block per node
__global__ __launch_bounds__(64) void k_bnaps(
    const float* __restrict__ x, const float* __restrict__ scale,
    const float* __restrict__ shift, const float* __restrict__ Ws,
    const float* __restrict__ Wd, float* __restrict__ hb, b16* __restrict__ hbb,
    float* __restrict__ es, float* __restrict__ ed) {
    int n = blockIdx.x, t = threadIdx.x;
    float2 xv = ((const float2*)(x + (size_t)n * HIDD))[t];
    float2 sc = ((const float2*)scale)[t];
    float2 sh = ((const float2*)shift)[t];
    float y0 = lrelu(xv.x * sc.x + sh.x, 0.1f);
    float y1 = lrelu(xv.y * sc.y + sh.y, 0.1f);
    ((float2*)(hb + (size_t)n * HIDD))[t] = make_float2(y0, y1);
    ushort2 ub; ub.x = f2b(y0); ub.y = f2b(y1);
    ((ushort2*)(hbb + (size_t)n * HIDD))[t] = ub;
    if (Ws) {
        float pe[4], pd[4];
        int tt = t * 2;
#pragma unroll
        for (int h = 0; h < 4; ++h) {
            pe[h] = y0 * Ws[h * 128 + tt] + y1 * Ws[h * 128 + tt + 1];
            pd[h] = y0 * Wd[h * 128 + tt] + y1 * Wd[h * 128 + tt + 1];
        }
#pragma unroll
        for (int off = 32; off > 0; off >>= 1) {
#pragma unroll
            for (int h = 0; h < 4; ++h) {
                pe[h] += __shfl_down(pe[h], off, 64);
                pd[h] += __shfl_down(pd[h], off, 64);
            }
        }
        if (t == 0) {
#pragma unroll
            for (int h = 0; h < 4; ++h) {
                es[n * 4 + h] = pe[h];
                ed[n * 4 + h] = pd[h];
            }
        }
    }
}

extern "C" void kernel_launch(void* const* d_in, const int* in_sizes, int n_in,
                              void* d_out, int out_size, void* d_ws, size_t ws_size,
                              hipStream_t stream) {
    const float* x = (const float*)d_in[0];
    const int* ei = (const int*)d_in[1];
    const int* src = ei;
    const int* dst = ei + NE;
    const int* etype = (const int*)d_in[2];
    const int* edist = (const int*)d_in[3];
    const float* W0 = (const float*)d_in[4];
    const float* asrc0 = (const float*)d_in[5];
    const float* adst0 = (const float*)d_in[6];
    const float* aedge0 = (const float*)d_in[7];
    const float* b0 = (const float*)d_in[8];
    const float* rel0 = (const float*)d_in[9];
    const float* Wm = (const float*)d_in[10];
    const float* asrcm = (const float*)d_in[11];
    const float* adstm = (const float*)d_in[12];
    const float* aedgem = (const float*)d_in[13];
    const float* bm = (const float*)d_in[14];
    const float* relm = (const float*)d_in[15];
    const float* WL = (const float*)d_in[16];
    const float* asrcL = (const float*)d_in[17];
    const float* adstL = (const float*)d_in[18];
    const float* aedgeL = (const float*)d_in[19];
    const float* bL = (const float*)d_in[20];
    const float* relL = (const float*)d_in[21];
    const float* bng = (const float*)d_in[22];
    const float* bnb = (const float*)d_in[23];
    float* out = (float*)d_out;

    char* w = (char*)d_ws;
    size_t off = 0;
    auto alloc = [&](size_t bytes) -> char* {
        char* p = w + off;
        off = (off + bytes + 255) & ~(size_t)255;
        return p;
    };
    char* ws0 = alloc((size_t)NN * FIN * 2);             // xb bf16 during prep; then xbuf/hb/hL
    b16* xb = (b16*)ws0;
    float* xbuf = (float*)ws0;                           // [NN][128] fp32
    float* hb = (float*)(ws0 + 10240000);                // [NN][128] fp32
    float* hL = (float*)(ws0 + 20480000);                // [NN][36]  fp32
    b16* h0b = (b16*)alloc((size_t)NN * 512 * 2);        // h0 bf16 / agg bf16
    b16* B0t = (b16*)alloc((size_t)512 * FIN * 2);
    b16* Bmt = (b16*)alloc((size_t)3 * HIDD * 512 * 2);
    b16* WLt = (b16*)alloc((size_t)48 * HIDD * 2);
    b16* hbb = (b16*)alloc((size_t)NN * HIDD * 2);
    float* es = (float*)alloc((size_t)NN * 4 * 4);
    float* ed = (float*)alloc((size_t)NN * 4 * 4);
    int* srcp = (int*)alloc((size_t)NE * 4);
    int* etpp = (int*)alloc((size_t)NE * 4);
    float* distwp = (float*)alloc((size_t)NE * 4);
    int* eidx = (int*)alloc((size_t)NE * 4);
    float* bnpart = (float*)alloc((size_t)200 * 256 * 4);
    float* scale = (float*)alloc(128 * 4);
    float* shift = (float*)alloc(128 * 4);
    float* wsmb = (float*)alloc(1536 * 4);
    float* wdmb = (float*)alloc(1536 * 4);
    float* etab = (float*)alloc(800 * 4);
    int* counts = (int*)alloc((size_t)NN * 4);
    int* rowptr = (int*)alloc((size_t)(NN + 1) * 4);
    int* cursor = (int*)alloc((size_t)NN * 4);

    const int B256 = 256;
    int gNE = (NE + 255) / 256;
    int gNN = (NN + 255) / 256;

    // CSR + permutation (once)
    k_zero<<<gNN, B256, 0, stream>>>((float*)counts, NN);
    k_count<<<gNE, B256, 0, stream>>>(dst, counts);
    k_scan<<<1, 1024, 0, stream>>>(counts, rowptr);
    k_copy_i32<<<gNN, B256, 0, stream>>>(cursor, rowptr, NN);
    k_fill<<<gNE, B256, 0, stream>>>(dst, cursor, eidx);
    k_permute<<<gNE, B256, 0, stream>>>(eidx, src, etype, edist, srcp, etpp, distwp);

    // tables + weight conversions
    k_etab<<<4, B256, 0, stream>>>(rel0, relm, relL, aedge0, aedgem, aedgeL, etab);
    k_wsm<<<12, B256, 0, stream>>>(Wm, asrcm, adstm, wsmb, wdmb);
    k_cast_bf16<<<(NN * FIN / 4 + 255) / 256, B256, 0, stream>>>(x, xb, NN * FIN / 4);
    k_convB0<<<(512 * FIN + 255) / 256, B256, 0, stream>>>(W0, B0t);
    k_convBm<<<(3 * HIDD * 512 + 255) / 256, B256, 0, stream>>>(Wm, Bmt);
    k_convBL<<<(48 * HIDD + 255) / 256, B256, 0, stream>>>(WL, WLt);

    int mblk = (NN + 127) / 128;  // 157

    // ---- conv0: MFMA GEMM w/ fused scores, then fused softmax+agg ----
    {
        dim3 g(mblk, 4);
        k_mfma_gemm<<<g, 256, 0, stream>>>(xb, B0t, NN, FIN, 512, 1.f, h0b, nullptr,
                                           nullptr, nullptr, asrc0, adst0, es, ed);
        k_agg0_f<<<NN, 64, 0, stream>>>(rowptr, srcp, etpp, distwp, es, ed, etab + 0,
                                        h0b, b0, xbuf);
    }

    // ---- 3 middle convs ----
    for (int i = 0; i < 3; ++i) {
        k_bnstats<<<200, 128, 0, stream>>>(xbuf, bnpart);
        k_bnfinal<<<1, 128, 0, stream>>>(bnpart, bng + i * 128, bnb + i * 128, scale, shift);
        k_bnaps<<<NN, 64, 0, stream>>>(xbuf, scale, shift, wsmb + i * 512, wdmb + i * 512,
                                       hb, hbb, es, ed);
        k_aggmid_f<<<NN, 64, 0, stream>>>(rowptr, srcp, etpp, distwp, es, ed,
                                          etab + (1 + i) * 160, hbb, h0b);
        dim3 g(mblk, 1);
        k_mfma_gemm<<<g, 256, 0, stream>>>(h0b, Bmt + (size_t)i * HIDD * 512, NN, 512, HIDD,
                                           0.25f, nullptr, xbuf, bm + i * 128, hb,
                                           nullptr, nullptr, nullptr, nullptr);
    }

    // ---- final conv ----
    {
        k_bnstats<<<200, 128, 0, stream>>>(xbuf, bnpart);
        k_bnfinal<<<1, 128, 0, stream>>>(bnpart, bng + 3 * 128, bnb + 3 * 128, scale, shift);
        k_bnaps<<<NN, 64, 0, stream>>>(xbuf, scale, shift, nullptr, nullptr, hb, hbb, es, ed);
        k_gemmL_mfma<<<(NN + 63) / 64, 256, 0, stream>>>(hbb, WLt, hL);
        k_scoresL<<<gNN, B256, 0, stream>>>(hL, asrcL, adstL, es, ed);
        k_aggL_f<<<NN, 64, 0, stream>>>(rowptr, srcp, etpp, distwp, es, ed, etab + 4 * 160,
                                        hL, bL, out);
    }
}

// Round 5
// 562.089 us; speedup vs baseline: 2.6729x; 1.1797x over previous
//
#include <hip/hip_runtime.h>
#include <math.h>

#define NN   20000
#define NE   320000
#define NH   4
#define NREL 40
#define FIN  768
#define HIDD 128
#define NCLS 9
#define MAXDEG 128

typedef __attribute__((ext_vector_type(8))) short short8;
typedef __attribute__((ext_vector_type(4))) float f32x4;
typedef unsigned short b16;

__device__ __forceinline__ float lrelu(float v, float s) { return v > 0.f ? v : v * s; }
__device__ __forceinline__ b16 f2b(float f) {
    unsigned int u = __float_as_uint(f);
    unsigned int r = u + 0x7FFFu + ((u >> 16) & 1u);
    return (b16)(r >> 16);
}
__device__ __forceinline__ float b2f(b16 u) { return __uint_as_float(((unsigned int)u) << 16); }

// ---------------- init: zero counts + all 4 BN sum slots ----------------
__global__ void k_init(int* __restrict__ counts, float* __restrict__ sums) {
    int i = blockIdx.x * blockDim.x + threadIdx.x;
    if (i < NN) counts[i] = 0;
    if (i < 1024) sums[i] = 0.f;
}
__global__ void k_copy_i32(int* d, const int* s, int n) {
    int i = blockIdx.x * blockDim.x + threadIdx.x;
    if (i < n) d[i] = s[i];
}

// ---------------- CSR build ----------------
__global__ void k_count(const int* __restrict__ dst, int* __restrict__ counts) {
    int e = blockIdx.x * blockDim.x + threadIdx.x;
    if (e < NE) atomicAdd(&counts[dst[e]], 1);
}
__global__ void k_scan(const int* __restrict__ counts, int* __restrict__ rowptr) {
    __shared__ int sh[1024];
    int t = threadIdx.x;
    int base = t * 20;
    int sum = 0;
    if (t < 1000) for (int k = 0; k < 20; ++k) sum += counts[base + k];
    sh[t] = sum;
    __syncthreads();
    for (int off = 1; off < 1024; off <<= 1) {
        int v = (t >= off) ? sh[t - off] : 0;
        __syncthreads();
        sh[t] += v;
        __syncthreads();
    }
    int ex = (t == 0) ? 0 : sh[t - 1];
    if (t == 0) rowptr[0] = 0;
    if (t < 1000) {
        int run = ex;
        for (int k = 0; k < 20; ++k) {
            run += counts[base + k];
            rowptr[base + k + 1] = run;
        }
    }
}
__global__ void k_fill(const int* __restrict__ dst, int* __restrict__ cursor, int* __restrict__ eidx) {
    int e = blockIdx.x * blockDim.x + threadIdx.x;
    if (e < NE) {
        int pos = atomicAdd(&cursor[dst[e]], 1);
        eidx[pos] = e;
    }
}
__global__ void k_permute(const int* __restrict__ eidx, const int* __restrict__ src,
                          const int* __restrict__ etype, const int* __restrict__ dist,
                          int* __restrict__ srcp, int* __restrict__ etp,
                          float* __restrict__ distwp) {
    int p = blockIdx.x * blockDim.x + threadIdx.x;
    if (p >= NE) return;
    int e = eidx[p];
    srcp[p] = src[e];
    etp[p] = etype[e];
    distwp[p] = 1.f / (1.f + (float)dist[e]);
}

// ---------------- fused small tables ----------------
// ids: [0,800) etab | [800,3872) wsm/wdm | [3872,10016) WLt | [10016,10112) aS48/aD48
__global__ void k_tables(const float* __restrict__ rel0, const float* __restrict__ relm,
                         const float* __restrict__ relL, const float* __restrict__ ae0,
                         const float* __restrict__ aem, const float* __restrict__ aeL,
                         const float* __restrict__ Wm, const float* __restrict__ asrcm,
                         const float* __restrict__ adstm, const float* __restrict__ WL,
                         const float* __restrict__ asrcL, const float* __restrict__ adstL,
                         float* __restrict__ etab, float* __restrict__ wsm,
                         float* __restrict__ wdm, b16* __restrict__ WLt,
                         float* __restrict__ aS48, float* __restrict__ aD48) {
    int id = blockIdx.x * blockDim.x + threadIdx.x;
    if (id < 800) {
        int tab = id / (NREL * NH);
        int rem = id % (NREL * NH);
        int t = rem >> 2, h = rem & 3;
        const float *rel, *ae;
        if (tab == 0)      { rel = rel0;                        ae = ae0; }
        else if (tab <= 3) { rel = relm + (tab - 1) * NREL * 2; ae = aem + (tab - 1) * NH * 2; }
        else               { rel = relL;                        ae = aeL; }
        etab[id] = rel[t * 2] * ae[h * 2] + rel[t * 2 + 1] * ae[h * 2 + 1];
    } else if (id < 3872) {
        int id2 = id - 800;
        int which = id2 / 1536;
        int r = id2 % 1536;
        int ih = r / HIDD;
        int f = r % HIDD;
        const float* w = Wm + ((size_t)ih * HIDD + f) * HIDD;
        const float* a = (which ? adstm : asrcm) + ih * HIDD;
        float acc = 0.f;
        for (int o = 0; o < HIDD; ++o) acc += w[o] * a[o];
        (which ? wdm : wsm)[r] = acc;
    } else if (id < 10016) {
        int id3 = id - 3872;
        int cf = id3 / HIDD, k = id3 % HIDD;
        float v = 0.f;
        if (cf < 36) {
            int h = cf / 9, c = cf % 9;
            v = WL[((size_t)h * HIDD + k) * NCLS + c];
        }
        WLt[id3] = f2b(v);
    } else if (id < 10112) {
        int id4 = id - 10016;
        int c = id4 % 48;
        float v = (c < 36) ? ((id4 < 48) ? asrcL[c] : adstL[c]) : 0.f;
        if (id4 < 48) aS48[c] = v; else aD48[c] = v;
    }
}

// ---------------- fused conversions: cast x + convB0 + convBm ----------------
// ids: [0,3840000) x float4-cast | [3840000,4233216) B0t | [4233216,4429824) Bmt
#define XCAST4   3840000
#define B0_END   4233216
#define BM_END   4429824
__global__ void k_casts(const float* __restrict__ x, const float* __restrict__ W0,
                        const float* __restrict__ Wm, b16* __restrict__ xb,
                        b16* __restrict__ B0t, b16* __restrict__ Bmt) {
    int id = blockIdx.x * blockDim.x + threadIdx.x;
    if (id < XCAST4) {
        float4 v = ((const float4*)x)[id];
        ushort4 o;
        o.x = f2b(v.x); o.y = f2b(v.y); o.z = f2b(v.z); o.w = f2b(v.w);
        ((ushort4*)xb)[id] = o;
    } else if (id < B0_END) {
        int i = id - XCAST4;
        int c = i / FIN, k = i % FIN;
        int h = c >> 7, o = c & 127;
        B0t[i] = f2b(W0[((size_t)h * FIN + k) * HIDD + o]);
    } else if (id < BM_END) {
        int i = id - B0_END;
        int l = i / (HIDD * 512);
        int r = i % (HIDD * 512);
        int o = r / 512, hf = r % 512;
        Bmt[i] = f2b(Wm[(size_t)l * 512 * HIDD + (size_t)hf * HIDD + o]);
    }
}

// ---------------- conv0 MFMA GEMM (bf16 out) + fused per-head scores ----------------
__global__ __launch_bounds__(256) void k_mfma_gemm(
    const b16* __restrict__ A, const b16* __restrict__ Bt, int M, int K, int N,
    b16* __restrict__ Cb, const float* __restrict__ asv, const float* __restrict__ adv,
    float* __restrict__ esp, float* __restrict__ edp) {
    __shared__ b16 As[128][40];
    __shared__ b16 Bs[128][40];
    __shared__ float sc_es[2][128];
    __shared__ float sc_ed[2][128];
    int tid = threadIdx.x;
    int lane = tid & 63, wave = tid >> 6;
    int wm = wave >> 1, wn = wave & 1;
    int l16 = lane & 15, quad = lane >> 4;
    int row0 = blockIdx.x * 128, col0 = blockIdx.y * 128;

    int c0 = tid, c1 = tid + 256;
    int ar0 = c0 >> 2, as0 = (c0 & 3) << 3;
    int ar1 = c1 >> 2, as1 = (c1 & 3) << 3;
    bool va0 = (row0 + ar0) < M, va1 = (row0 + ar1) < M;
    const b16* Ap0 = A + (size_t)(row0 + ar0) * K + as0;
    const b16* Ap1 = A + (size_t)(row0 + ar1) * K + as1;
    const b16* Bp0 = Bt + (size_t)(col0 + ar0) * K + as0;
    const b16* Bp1 = Bt + (size_t)(col0 + ar1) * K + as1;

    f32x4 acc[4][4];
#pragma unroll
    for (int i = 0; i < 4; ++i)
#pragma unroll
        for (int j = 0; j < 4; ++j) acc[i][j] = (f32x4){0.f, 0.f, 0.f, 0.f};
    short8 zz = {0, 0, 0, 0, 0, 0, 0, 0};

    for (int kt = 0; kt < K; kt += 32) {
        short8 a0 = va0 ? *(const short8*)(Ap0 + kt) : zz;
        short8 a1 = va1 ? *(const short8*)(Ap1 + kt) : zz;
        short8 b0 = *(const short8*)(Bp0 + kt);
        short8 b1 = *(const short8*)(Bp1 + kt);
        __syncthreads();
        *(short8*)&As[ar0][as0] = a0;
        *(short8*)&As[ar1][as1] = a1;
        *(short8*)&Bs[ar0][as0] = b0;
        *(short8*)&Bs[ar1][as1] = b1;
        __syncthreads();
        short8 bf[4];
#pragma unroll
        for (int ni = 0; ni < 4; ++ni)
            bf[ni] = *(const short8*)&Bs[wn * 64 + ni * 16 + l16][quad * 8];
#pragma unroll
        for (int mi = 0; mi < 4; ++mi) {
            short8 af = *(const short8*)&As[wm * 64 + mi * 16 + l16][quad * 8];
#pragma unroll
            for (int ni = 0; ni < 4; ++ni)
                acc[mi][ni] = __builtin_amdgcn_mfma_f32_16x16x32_bf16(af, bf[ni], acc[mi][ni], 0, 0, 0);
        }
    }
#pragma unroll
    for (int mi = 0; mi < 4; ++mi) {
        int rb = row0 + wm * 64 + mi * 16 + quad * 4;
#pragma unroll
        for (int ni = 0; ni < 4; ++ni) {
            int c = col0 + wn * 64 + ni * 16 + l16;
#pragma unroll
            for (int r = 0; r < 4; ++r) {
                int row = rb + r;
                if (row < M) Cb[(size_t)row * N + c] = f2b(acc[mi][ni][r]);
            }
        }
    }
    // fused scores: col-block == head
    {
        int h = blockIdx.y;
        float as_c[4], ad_c[4];
#pragma unroll
        for (int ni = 0; ni < 4; ++ni) {
            int c = wn * 64 + ni * 16 + l16;
            as_c[ni] = asv[h * 128 + c];
            ad_c[ni] = adv[h * 128 + c];
        }
#pragma unroll
        for (int mi = 0; mi < 4; ++mi) {
#pragma unroll
            for (int r = 0; r < 4; ++r) {
                float pes = 0.f, ped = 0.f;
#pragma unroll
                for (int ni = 0; ni < 4; ++ni) {
                    float v = acc[mi][ni][r];
                    pes += v * as_c[ni];
                    ped += v * ad_c[ni];
                }
#pragma unroll
                for (int m = 1; m < 16; m <<= 1) {
                    pes += __shfl_xor(pes, m, 64);
                    ped += __shfl_xor(ped, m, 64);
                }
                if (l16 == 0) {
                    int rl = wm * 64 + mi * 16 + quad * 4 + r;
                    sc_es[wn][rl] = pes;
                    sc_ed[wn][rl] = ped;
                }
            }
        }
        __syncthreads();
        if (tid < 128) {
            int row = row0 + tid;
            if (row < M) {
                esp[row * 4 + h] = sc_es[0][tid] + sc_es[1][tid];
                edp[row * 4 + h] = sc_ed[0][tid] + sc_ed[1][tid];
            }
        }
    }
}

// ---------------- mid MFMA GEMM 64x128 tile + fused BN stats ----------------
__global__ __launch_bounds__(128) void k_gemm_mid(
    const b16* __restrict__ A, const b16* __restrict__ Bt, float* __restrict__ Cf,
    const float* __restrict__ bias, const float* __restrict__ resid,
    float* __restrict__ sums) {
    __shared__ b16 As[64][40];
    __shared__ b16 Bs[128][40];
    int tid = threadIdx.x;
    int lane = tid & 63, wave = tid >> 6;  // wave = col-half
    int l16 = lane & 15, quad = lane >> 4;
    int row0 = blockIdx.x * 64;
    const int K = 512;

    int ar[2], asg[2]; bool av[2];
    const b16* Ap[2];
#pragma unroll
    for (int j = 0; j < 2; ++j) {
        int c = tid + j * 128;
        ar[j] = c >> 2; asg[j] = (c & 3) << 3;
        int grow = row0 + ar[j];
        av[j] = grow < NN;
        Ap[j] = A + (size_t)(av[j] ? grow : 0) * K + asg[j];
    }
    int br[4], bsg[4];
    const b16* Bp[4];
#pragma unroll
    for (int j = 0; j < 4; ++j) {
        int c = tid + j * 128;
        br[j] = c >> 2; bsg[j] = (c & 3) << 3;
        Bp[j] = Bt + (size_t)br[j] * K + bsg[j];
    }

    f32x4 acc[4][4];
#pragma unroll
    for (int i = 0; i < 4; ++i)
#pragma unroll
        for (int j = 0; j < 4; ++j) acc[i][j] = (f32x4){0.f, 0.f, 0.f, 0.f};
    short8 zz = {0, 0, 0, 0, 0, 0, 0, 0};

    for (int kt = 0; kt < K; kt += 32) {
        short8 a[2], b[4];
#pragma unroll
        for (int j = 0; j < 2; ++j) a[j] = av[j] ? *(const short8*)(Ap[j] + kt) : zz;
#pragma unroll
        for (int j = 0; j < 4; ++j) b[j] = *(const short8*)(Bp[j] + kt);
        __syncthreads();
#pragma unroll
        for (int j = 0; j < 2; ++j) *(short8*)&As[ar[j]][asg[j]] = a[j];
#pragma unroll
        for (int j = 0; j < 4; ++j) *(short8*)&Bs[br[j]][bsg[j]] = b[j];
        __syncthreads();
        short8 bf[4];
#pragma unroll
        for (int ni = 0; ni < 4; ++ni)
            bf[ni] = *(const short8*)&Bs[wave * 64 + ni * 16 + l16][quad * 8];
#pragma unroll
        for (int mi = 0; mi < 4; ++mi) {
            short8 af = *(const short8*)&As[mi * 16 + l16][quad * 8];
#pragma unroll
            for (int ni = 0; ni < 4; ++ni)
                acc[mi][ni] = __builtin_amdgcn_mfma_f32_16x16x32_bf16(af, bf[ni], acc[mi][ni], 0, 0, 0);
        }
    }
    float sp[4] = {0.f, 0.f, 0.f, 0.f}, qp[4] = {0.f, 0.f, 0.f, 0.f};
#pragma unroll
    for (int mi = 0; mi < 4; ++mi) {
        int rb = row0 + mi * 16 + quad * 4;
#pragma unroll
        for (int ni = 0; ni < 4; ++ni) {
            int c = wave * 64 + ni * 16 + l16;
#pragma unroll
            for (int r = 0; r < 4; ++r) {
                int row = rb + r;
                if (row < NN) {
                    float v = acc[mi][ni][r] * 0.25f + bias[c] + resid[(size_t)row * HIDD + c];
                    Cf[(size_t)row * HIDD + c] = v;
                    sp[ni] += v;
                    qp[ni] += v * v;
                }
            }
        }
    }
#pragma unroll
    for (int ni = 0; ni < 4; ++ni) {
        float s = sp[ni], q = qp[ni];
        s += __shfl_xor(s, 16, 64); s += __shfl_xor(s, 32, 64);
        q += __shfl_xor(q, 16, 64); q += __shfl_xor(q, 32, 64);
        if (quad == 0) {
            int c = wave * 64 + ni * 16 + l16;
            atomicAdd(&sums[c], s);
            atomicAdd(&sums[128 + c], q);
        }
    }
}

// ---------------- gemmL via MFMA + fused final scores ----------------
__global__ __launch_bounds__(256) void k_gemmL_mfma(
    const b16* __restrict__ hbb, const b16* __restrict__ WLt, float* __restrict__ hL,
    const float* __restrict__ aS48, const float* __restrict__ aD48,
    float* __restrict__ es, float* __restrict__ ed) {
    int tid = threadIdx.x;
    int lane = tid & 63, wave = tid >> 6;
    int l16 = lane & 15, quad = lane >> 4;
    int base = blockIdx.x * 64 + wave * 16;
    int na = base + l16;
    f32x4 acc[3];
#pragma unroll
    for (int ct = 0; ct < 3; ++ct) acc[ct] = (f32x4){0.f, 0.f, 0.f, 0.f};
    short8 zz = {0, 0, 0, 0, 0, 0, 0, 0};
#pragma unroll
    for (int k0 = 0; k0 < 128; k0 += 32) {
        short8 af = (na < NN) ? *(const short8*)(hbb + (size_t)na * HIDD + k0 + quad * 8) : zz;
#pragma unroll
        for (int ct = 0; ct < 3; ++ct) {
            short8 bf = *(const short8*)(WLt + (size_t)(ct * 16 + l16) * HIDD + k0 + quad * 8);
            acc[ct] = __builtin_amdgcn_mfma_f32_16x16x32_bf16(af, bf, acc[ct], 0, 0, 0);
        }
    }
#pragma unroll
    for (int ct = 0; ct < 3; ++ct) {
        int col = ct * 16 + l16;
        if (col < 36) {
#pragma unroll
            for (int r = 0; r < 4; ++r) {
                int row = base + quad * 4 + r;
                if (row < NN) hL[(size_t)row * 36 + col] = acc[ct][r];
            }
        }
    }
    // fused scores: es/ed per head (cols padded >=36 have aS48=0)
    float asv[3], adv[3]; int hh[3];
#pragma unroll
    for (int ct = 0; ct < 3; ++ct) {
        int col = ct * 16 + l16;
        asv[ct] = aS48[col];
        adv[ct] = aD48[col];
        hh[ct] = (col < 36) ? (col / 9) : 0;
    }
#pragma unroll
    for (int r = 0; r < 4; ++r) {
        float pes[4] = {0.f, 0.f, 0.f, 0.f}, ped[4] = {0.f, 0.f, 0.f, 0.f};
#pragma unroll
        for (int ct = 0; ct < 3; ++ct) {
            float vs = acc[ct][r] * asv[ct];
            float vd = acc[ct][r] * adv[ct];
#pragma unroll
            for (int h = 0; h < 4; ++h) {
                pes[h] += (hh[ct] == h) ? vs : 0.f;
                ped[h] += (hh[ct] == h) ? vd : 0.f;
            }
        }
#pragma unroll
        for (int m = 1; m < 16; m <<= 1) {
#pragma unroll
            for (int h = 0; h < 4; ++h) {
                pes[h] += __shfl_xor(pes[h], m, 64);
                ped[h] += __shfl_xor(ped[h], m, 64);
            }
        }
        if (l16 == 0) {
            int row = base + quad * 4 + r;
            if (row < NN) {
#pragma unroll
                for (int h = 0; h < 4; ++h) {
                    es[row * 4 + h] = pes[h];
                    ed[row * 4 + h] = ped[h];
                }
            }
        }
    }
}

// ---------------- fused edge-softmax + aggregation ----------------
// conv0: gather bf16 h0 rows (512-wide, ushort4, half-block seg split)
__global__ __launch_bounds__(64) void k_agg0_f(
    const int* __restrict__ rowptr, const int* __restrict__ srcp,
    const int* __restrict__ etpp, const float* __restrict__ distwp,
    const float* __restrict__ es, const float* __restrict__ ed,
    const float* __restrict__ etab, const b16* __restrict__ h0b,
    const float* __restrict__ b0, float* __restrict__ xout) {
    __shared__ float4 exw[MAXDEG];
    __shared__ float comb[32][4];
    int n = blockIdx.x, t = threadIdx.x;
    int p0 = rowptr[n], p1 = rowptr[n + 1];
    int deg = p1 - p0;
    float4 edn = ((const float4*)ed)[n];
    float d0 = 0.f, d1 = 0.f, d2 = 0.f, d3 = 0.f;
    for (int p = p0 + t; p < p1; p += 64) {
        int s = srcp[p], ty = etpp[p];
        float w = distwp[p];
        float4 a = ((const float4*)es)[s];
        float4 c = ((const float4*)etab)[ty];
        float e0 = __expf(lrelu(a.x + edn.x + c.x, 0.2f));
        float e1 = __expf(lrelu(a.y + edn.y + c.y, 0.2f));
        float e2 = __expf(lrelu(a.z + edn.z + c.z, 0.2f));
        float e3 = __expf(lrelu(a.w + edn.w + c.w, 0.2f));
        d0 += e0; d1 += e1; d2 += e2; d3 += e3;
        int ix = p - p0;
        if (ix < MAXDEG) exw[ix] = make_float4(e0 * w, e1 * w, e2 * w, e3 * w);
    }
#pragma unroll
    for (int off = 32; off > 0; off >>= 1) {
        d0 += __shfl_down(d0, off, 64);
        d1 += __shfl_down(d1, off, 64);
        d2 += __shfl_down(d2, off, 64);
        d3 += __shfl_down(d3, off, 64);
    }
    d0 = __shfl(d0, 0, 64); d1 = __shfl(d1, 0, 64);
    d2 = __shfl(d2, 0, 64); d3 = __shfl(d3, 0, 64);
    float r0 = 1.f / (d0 + 1e-16f), r1 = 1.f / (d1 + 1e-16f);
    float r2 = 1.f / (d2 + 1e-16f), r3 = 1.f / (d3 + 1e-16f);
    __syncthreads();
    int half = t >> 5, q = t & 31;
    int cq = q * 4;
    float ra = half ? r2 : r0, rb = half ? r3 : r1;
    int sega = half * 256;  // head offset in elements
    float acc[4] = {0.f, 0.f, 0.f, 0.f};
    if (deg <= MAXDEG) {
        int p = p0;
        for (; p + 4 <= p1; p += 4) {
            int ss[4]; float4 ee[4];
#pragma unroll
            for (int j = 0; j < 4; ++j) { ss[j] = srcp[p + j]; ee[j] = exw[p - p0 + j]; }
#pragma unroll
            for (int j = 0; j < 4; ++j) {
                float ca = (half ? ee[j].z : ee[j].x) * ra;
                float cb = (half ? ee[j].w : ee[j].y) * rb;
                const b16* hr = h0b + (size_t)ss[j] * 512 + sega + cq;
                ushort4 ua = *(const ushort4*)(hr);
                ushort4 ub = *(const ushort4*)(hr + 128);
                acc[0] += ca * b2f(ua.x) + cb * b2f(ub.x);
                acc[1] += ca * b2f(ua.y) + cb * b2f(ub.y);
                acc[2] += ca * b2f(ua.z) + cb * b2f(ub.z);
                acc[3] += ca * b2f(ua.w) + cb * b2f(ub.w);
            }
        }
        for (; p < p1; ++p) {
            int s = srcp[p];
            float4 e = exw[p - p0];
            float ca = (half ? e.z : e.x) * ra;
            float cb = (half ? e.w : e.y) * rb;
            const b16* hr = h0b + (size_t)s * 512 + sega + cq;
            ushort4 ua = *(const ushort4*)(hr);
            ushort4 ub = *(const ushort4*)(hr + 128);
            acc[0] += ca * b2f(ua.x) + cb * b2f(ub.x);
            acc[1] += ca * b2f(ua.y) + cb * b2f(ub.y);
            acc[2] += ca * b2f(ua.z) + cb * b2f(ub.z);
            acc[3] += ca * b2f(ua.w) + cb * b2f(ub.w);
        }
    } else {
        for (int p = p0; p < p1; ++p) {
            int s = srcp[p];
            int ix = p - p0;
            float4 e;
            if (ix < MAXDEG) e = exw[ix];
            else {
                int ty = etpp[p];
                float w = distwp[p];
                float4 a = ((const float4*)es)[s];
                float4 c = ((const float4*)etab)[ty];
                e.x = __expf(lrelu(a.x + edn.x + c.x, 0.2f)) * w;
                e.y = __expf(lrelu(a.y + edn.y + c.y, 0.2f)) * w;
                e.z = __expf(lrelu(a.z + edn.z + c.z, 0.2f)) * w;
                e.w = __expf(lrelu(a.w + edn.w + c.w, 0.2f)) * w;
            }
            float ca = (half ? e.z : e.x) * ra;
            float cb = (half ? e.w : e.y) * rb;
            const b16* hr = h0b + (size_t)s * 512 + sega + cq;
            ushort4 ua = *(const ushort4*)(hr);
            ushort4 ub = *(const ushort4*)(hr + 128);
            acc[0] += ca * b2f(ua.x) + cb * b2f(ub.x);
            acc[1] += ca * b2f(ua.y) + cb * b2f(ub.y);
            acc[2] += ca * b2f(ua.z) + cb * b2f(ub.z);
            acc[3] += ca * b2f(ua.w) + cb * b2f(ub.w);
        }
    }
    if (half == 1) {
        comb[q][0] = acc[0]; comb[q][1] = acc[1];
        comb[q][2] = acc[2]; comb[q][3] = acc[3];
    }
    __syncthreads();
    if (half == 0) {
        float4 o;
        o.x = 0.25f * (acc[0] + comb[q][0]) + b0[cq];
        o.y = 0.25f * (acc[1] + comb[q][1]) + b0[cq + 1];
        o.z = 0.25f * (acc[2] + comb[q][2]) + b0[cq + 2];
        o.w = 0.25f * (acc[3] + comb[q][3]) + b0[cq + 3];
        *(float4*)(xout + (size_t)n * HIDD + cq) = o;
    }
}
// mid: gather bf16 hb rows (128-wide, ushort4, half-block edge split)
__global__ __launch_bounds__(64) void k_aggmid_f(
    const int* __restrict__ rowptr, const int* __restrict__ srcp,
    const int* __restrict__ etpp, const float* __restrict__ distwp,
    const float* __restrict__ es, const float* __restrict__ ed,
    const float* __restrict__ etab, const b16* __restrict__ hbb,
    b16* __restrict__ aggb) {
    __shared__ float4 exw[MAXDEG];
    __shared__ float comb[32][16];
    int n = blockIdx.x, t = threadIdx.x;
    int p0 = rowptr[n], p1 = rowptr[n + 1];
    int deg = p1 - p0;
    float4 edn = ((const float4*)ed)[n];
    float d0 = 0.f, d1 = 0.f, d2 = 0.f, d3 = 0.f;
    for (int p = p0 + t; p < p1; p += 64) {
        int s = srcp[p], ty = etpp[p];
        float w = distwp[p];
        float4 a = ((const float4*)es)[s];
        float4 c = ((const float4*)etab)[ty];
        float e0 = __expf(lrelu(a.x + edn.x + c.x, 0.2f));
        float e1 = __expf(lrelu(a.y + edn.y + c.y, 0.2f));
        float e2 = __expf(lrelu(a.z + edn.z + c.z, 0.2f));
        float e3 = __expf(lrelu(a.w + edn.w + c.w, 0.2f));
        d0 += e0; d1 += e1; d2 += e2; d3 += e3;
        int ix = p - p0;
        if (ix < MAXDEG) exw[ix] = make_float4(e0 * w, e1 * w, e2 * w, e3 * w);
    }
#pragma unroll
    for (int off = 32; off > 0; off >>= 1) {
        d0 += __shfl_down(d0, off, 64);
        d1 += __shfl_down(d1, off, 64);
        d2 += __shfl_down(d2, off, 64);
        d3 += __shfl_down(d3, off, 64);
    }
    d0 = __shfl(d0, 0, 64); d1 = __shfl(d1, 0, 64);
    d2 = __shfl(d2, 0, 64); d3 = __shfl(d3, 0, 64);
    float r0 = 1.f / (d0 + 1e-16f), r1 = 1.f / (d1 + 1e-16f);
    float r2 = 1.f / (d2 + 1e-16f), r3 = 1.f / (d3 + 1e-16f);
    __syncthreads();
    int half = t >> 5, q = t & 31;
    int cq = q * 4;
    float acc[4][4];
#pragma unroll
    for (int h = 0; h < 4; ++h)
#pragma unroll
        for (int j = 0; j < 4; ++j) acc[h][j] = 0.f;
    auto doE = [&](int s, float4 e) {
        float c0 = e.x * r0, c1 = e.y * r1, c2 = e.z * r2, c3 = e.w * r3;
        ushort4 u = *(const ushort4*)(hbb + (size_t)s * HIDD + cq);
        float f0 = b2f(u.x), f1 = b2f(u.y), f2 = b2f(u.z), f3 = b2f(u.w);
        acc[0][0] += c0 * f0; acc[0][1] += c0 * f1; acc[0][2] += c0 * f2; acc[0][3] += c0 * f3;
        acc[1][0] += c1 * f0; acc[1][1] += c1 * f1; acc[1][2] += c1 * f2; acc[1][3] += c1 * f3;
        acc[2][0] += c2 * f0; acc[2][1] += c2 * f1; acc[2][2] += c2 * f2; acc[2][3] += c2 * f3;
        acc[3][0] += c3 * f0; acc[3][1] += c3 * f1; acc[3][2] += c3 * f2; acc[3][3] += c3 * f3;
    };
    if (deg <= MAXDEG) {
        int p = p0 + half;
        for (; p + 2 < p1; p += 4) {
            int s0 = srcp[p], s1 = srcp[p + 2];
            float4 e0 = exw[p - p0], e1 = exw[p + 2 - p0];
            doE(s0, e0);
            doE(s1, e1);
        }
        for (; p < p1; p += 2) doE(srcp[p], exw[p - p0]);
    } else {
        for (int p = p0 + half; p < p1; p += 2) {
            int s = srcp[p];
            int ix = p - p0;
            float4 e;
            if (ix < MAXDEG) e = exw[ix];
            else {
                int ty = etpp[p];
                float w = distwp[p];
                float4 a = ((const float4*)es)[s];
                float4 c = ((const float4*)etab)[ty];
                e.x = __expf(lrelu(a.x + edn.x + c.x, 0.2f)) * w;
                e.y = __expf(lrelu(a.y + edn.y + c.y, 0.2f)) * w;
                e.z = __expf(lrelu(a.z + edn.z + c.z, 0.2f)) * w;
                e.w = __expf(lrelu(a.w + edn.w + c.w, 0.2f)) * w;
            }
            doE(s, e);
        }
    }
    if (half == 1) {
#pragma unroll
        for (int h = 0; h < 4; ++h)
#pragma unroll
            for (int j = 0; j < 4; ++j) comb[q][h * 4 + j] = acc[h][j];
    }
    __syncthreads();
    if (half == 0) {
        b16* o = aggb + (size_t)n * 512;
#pragma unroll
        for (int h = 0; h < 4; ++h) {
            ushort4 w4;
            w4.x = f2b(acc[h][0] + comb[q][h * 4 + 0]);
            w4.y = f2b(acc[h][1] + comb[q][h * 4 + 1]);
            w4.z = f2b(acc[h][2] + comb[q][h * 4 + 2]);
            w4.w = f2b(acc[h][3] + comb[q][h * 4 + 3]);
            *(ushort4*)(o + h * 128 + cq) = w4;
        }
    }
}
// final: gather fp32 hL rows (36-wide), fused mean+bias+lrelu
__global__ __launch_bounds__(64) void k_aggL_f(
    const int* __restrict__ rowptr, const int* __restrict__ srcp,
    const int* __restrict__ etpp, const float* __restrict__ distwp,
    const float* __restrict__ es, const float* __restrict__ ed,
    const float* __restrict__ etab, const float* __restrict__ hL,
    const float* __restrict__ bL, float* __restrict__ out) {
    __shared__ float4 exw[MAXDEG];
    __shared__ float sh[40];
    int n = blockIdx.x, t = threadIdx.x;
    int p0 = rowptr[n], p1 = rowptr[n + 1];
    int deg = p1 - p0;
    float4 edn = ((const float4*)ed)[n];
    float d0 = 0.f, d1 = 0.f, d2 = 0.f, d3 = 0.f;
    for (int p = p0 + t; p < p1; p += 64) {
        int s = srcp[p], ty = etpp[p];
        float w = distwp[p];
        float4 a = ((const float4*)es)[s];
        float4 c = ((const float4*)etab)[ty];
        float e0 = __expf(lrelu(a.x + edn.x + c.x, 0.2f));
        float e1 = __expf(lrelu(a.y + edn.y + c.y, 0.2f));
        float e2 = __expf(lrelu(a.z + edn.z + c.z, 0.2f));
        float e3 = __expf(lrelu(a.w + edn.w + c.w, 0.2f));
        d0 += e0; d1 += e1; d2 += e2; d3 += e3;
        int ix = p - p0;
        if (ix < MAXDEG) exw[ix] = make_float4(e0 * w, e1 * w, e2 * w, e3 * w);
    }
#pragma unroll
    for (int off = 32; off > 0; off >>= 1) {
        d0 += __shfl_down(d0, off, 64);
        d1 += __shfl_down(d1, off, 64);
        d2 += __shfl_down(d2, off, 64);
        d3 += __shfl_down(d3, off, 64);
    }
    d0 = __shfl(d0, 0, 64); d1 = __shfl(d1, 0, 64);
    d2 = __shfl(d2, 0, 64); d3 = __shfl(d3, 0, 64);
    __syncthreads();
    if (t < 36) {
        int hh = t / 9;
        float rv = (hh == 0) ? 1.f / (d0 + 1e-16f)
                 : (hh == 1) ? 1.f / (d1 + 1e-16f)
                 : (hh == 2) ? 1.f / (d2 + 1e-16f)
                             : 1.f / (d3 + 1e-16f);
        float acc = 0.f;
        if (deg <= MAXDEG) {
            int p = p0;
            for (; p + 4 <= p1; p += 4) {
                int ss[4]; float aw[4];
#pragma unroll
                for (int j = 0; j < 4; ++j) {
                    ss[j] = srcp[p + j];
                    float4 e = exw[p - p0 + j];
                    aw[j] = (hh == 0) ? e.x : (hh == 1) ? e.y : (hh == 2) ? e.z : e.w;
                }
                float g[4];
#pragma unroll
                for (int j = 0; j < 4; ++j) g[j] = hL[(size_t)ss[j] * 36 + t];
#pragma unroll
                for (int j = 0; j < 4; ++j) acc += aw[j] * g[j];
            }
            for (; p < p1; ++p) {
                float4 e = exw[p - p0];
                float av = (hh == 0) ? e.x : (hh == 1) ? e.y : (hh == 2) ? e.z : e.w;
                acc += av * hL[(size_t)srcp[p] * 36 + t];
            }
        } else {
            for (int p = p0; p < p1; ++p) {
                int s = srcp[p];
                int ix = p - p0;
                float av;
                if (ix < MAXDEG) {
                    float4 e = exw[ix];
                    av = (hh == 0) ? e.x : (hh == 1) ? e.y : (hh == 2) ? e.z : e.w;
                } else {
                    int ty = etpp[p];
                    float w = distwp[p];
                    float4 a = ((const float4*)es)[s];
                    float4 c = ((const float4*)etab)[ty];
                    float lv = (hh == 0) ? a.x + edn.x + c.x
                             : (hh == 1) ? a.y + edn.y + c.y
                             : (hh == 2) ? a.z + edn.z + c.z
                                         : a.w + edn.w + c.w;
                    av = __expf(lrelu(lv, 0.2f)) * w;
                }
                acc += av * hL[(size_t)s * 36 + t];
            }
        }
        sh[t] = acc * rv;
    }
    __syncthreads();
    if (t < 9) {
        float v = 0.25f * (sh[t] + sh[t + 9] + sh[t + 18] + sh[t + 27]) + bL[t];
        out[(size_t)n * 9 + t] = lrelu(v, 0.1f);
    }
}

// ---------------- BN stats (layer 1 only; atomic into sums slot 0) ----------------
__global__ __launch_bounds__(128) void k_bnstats_at(const float* __restrict__ x,
                                                    float* __restrict__ sums) {
    int f = threadIdx.x;
    float s = 0.f, q = 0.f;
    for (int r = blockIdx.x; r < NN; r += 200) {
        float v = x[(size_t)r * HIDD + f];
        s += v;
        q += v * v;
    }
    atomicAdd(&sums[f], s);
    atomicAdd(&sums[128 + f], q);
}
// BN apply with inline scale/shift from sums + optional fused mid scores
__global__ __launch_bounds__(64) void k_bnaps(
    const float* __restrict__ x, const float* __restrict__ sums,
    const float* __restrict__ gamma, const float* __restrict__ beta,
    const float* __restrict__ Ws, const float* __restrict__ Wd,
    float* __restrict__ hb, b16* __restrict__ hbb,
    float* __restrict__ es, float* __restrict__ ed) {
    int n = blockIdx.x, t = threadIdx.x;
    int c0 = t * 2;
    float s0 = sums[c0], s1 = sums[c0 + 1];
    float q0 = sums[128 + c0], q1 = sums[128 + c0 + 1];
    float m0 = s0 * (1.f / NN), m1 = s1 * (1.f / NN);
    float v0 = q0 * (1.f / NN) - m0 * m0, v1 = q1 * (1.f / NN) - m1 * m1;
    float sc0 = gamma[c0] * rsqrtf(v0 + 1e-5f);
    float sc1 = gamma[c0 + 1] * rsqrtf(v1 + 1e-5f);
    float sh0 = beta[c0] - m0 * sc0, sh1 = beta[c0 + 1] - m1 * sc1;
    float2 xv = ((const float2*)(x + (size_t)n * HIDD))[t];
    float y0 = lrelu(xv.x * sc0 + sh0, 0.1f);
    float y1 = lrelu(xv.y * sc1 + sh1, 0.1f);
    ((float2*)(hb + (size_t)n * HIDD))[t] = make_float2(y0, y1);
    ushort2 ub; ub.x = f2b(y0); ub.y = f2b(y1);
    ((ushort2*)(hbb + (size_t)n * HIDD))[t] = ub;
    if (Ws) {
        float pe[4], pd[4];
#pragma unroll
        for (int h = 0; h < 4; ++h) {
            pe[h] = y0 * Ws[h * 128 + c0] + y1 * Ws[h * 128 + c0 + 1];
            pd[h] = y0 * Wd[h * 128 + c0] + y1 * Wd[h * 128 + c0 + 1];
        }
#pragma unroll
        for (int off = 32; off > 0; off >>= 1) {
#pragma unroll
            for (int h = 0; h < 4; ++h) {
                pe[h] += __shfl_down(pe[h], off, 64);
                pd[h] += __shfl_down(pd[h], off, 64);
            }
        }
        if (t == 0) {
#pragma unroll
            for (int h = 0; h < 4; ++h) {
                es[n * 4 + h] = pe[h];
                ed[n * 4 + h] = pd[h];
            }
        }
    }
}

extern "C" void kernel_launch(void* const* d_in, const int* in_sizes, int n_in,
                              void* d_out, int out_size, void* d_ws, size_t ws_size,
                              hipStream_t stream) {
    const float* x = (const float*)d_in[0];
    const int* ei = (const int*)d_in[1];
    const int* src = ei;
    const int* dst = ei + NE;
    const int* etype = (const int*)d_in[2];
    const int* edist = (const int*)d_in[3];
    const float* W0 = (const float*)d_in[4];
    const float* asrc0 = (const float*)d_in[5];
    const float* adst0 = (const float*)d_in[6];
    const float* aedge0 = (const float*)d_in[7];
    const float* b0 = (const float*)d_in[8];
    const float* rel0 = (const float*)d_in[9];
    const float* Wm = (const float*)d_in[10];
    const float* asrcm = (const float*)d_in[11];
    const float* adstm = (const float*)d_in[12];
    const float* aedgem = (const float*)d_in[13];
    const float* bm = (const float*)d_in[14];
    const float* relm = (const float*)d_in[15];
    const float* WL = (const float*)d_in[16];
    const float* asrcL = (const float*)d_in[17];
    const float* adstL = (const float*)d_in[18];
    const float* aedgeL = (const float*)d_in[19];
    const float* bL = (const float*)d_in[20];
    const float* relL = (const float*)d_in[21];
    const float* bng = (const float*)d_in[22];
    const float* bnb = (const float*)d_in[23];
    float* out = (float*)d_out;

    char* w = (char*)d_ws;
    size_t off = 0;
    auto alloc = [&](size_t bytes) -> char* {
        char* p = w + off;
        off = (off + bytes + 255) & ~(size_t)255;
        return p;
    };
    char* ws0 = alloc((size_t)NN * FIN * 2);             // xb bf16 during prep; then xbuf/hb/hL
    b16* xb = (b16*)ws0;
    float* xbuf = (float*)ws0;                           // [NN][128] fp32
    float* hb = (float*)(ws0 + 10240000);                // [NN][128] fp32
    float* hL = (float*)(ws0 + 20480000);                // [NN][36]  fp32
    b16* h0b = (b16*)alloc((size_t)NN * 512 * 2);        // h0 bf16 / agg bf16
    b16* B0t = (b16*)alloc((size_t)512 * FIN * 2);
    b16* Bmt = (b16*)alloc((size_t)3 * HIDD * 512 * 2);
    b16* WLt = (b16*)alloc((size_t)48 * HIDD * 2);
    b16* hbb = (b16*)alloc((size_t)NN * HIDD * 2);
    float* es = (float*)alloc((size_t)NN * 4 * 4);
    float* ed = (float*)alloc((size_t)NN * 4 * 4);
    int* srcp = (int*)alloc((size_t)NE * 4);
    int* etpp = (int*)alloc((size_t)NE * 4);
    float* distwp = (float*)alloc((size_t)NE * 4);
    int* eidx = (int*)alloc((size_t)NE * 4);
    float* sums = (float*)alloc(1024 * 4);               // 4 slots x 256
    float* wsmb = (float*)alloc(1536 * 4);
    float* wdmb = (float*)alloc(1536 * 4);
    float* etab = (float*)alloc(800 * 4);
    float* aS48 = (float*)alloc(48 * 4);
    float* aD48 = (float*)alloc(48 * 4);
    int* counts = (int*)alloc((size_t)NN * 4);
    int* rowptr = (int*)alloc((size_t)(NN + 1) * 4);
    int* cursor = (int*)alloc((size_t)NN * 4);

    const int B256 = 256;
    int gNE = (NE + 255) / 256;
    int gNN = (NN + 255) / 256;

    // CSR + permutation + zero init
    k_init<<<gNN, B256, 0, stream>>>(counts, sums);
    k_count<<<gNE, B256, 0, stream>>>(dst, counts);
    k_scan<<<1, 1024, 0, stream>>>(counts, rowptr);
    k_copy_i32<<<gNN, B256, 0, stream>>>(cursor, rowptr, NN);
    k_fill<<<gNE, B256, 0, stream>>>(dst, cursor, eidx);
    k_permute<<<gNE, B256, 0, stream>>>(eidx, src, etype, edist, srcp, etpp, distwp);

    // fused tables + conversions
    k_tables<<<(10112 + 255) / 256, B256, 0, stream>>>(
        rel0, relm, relL, aedge0, aedgem, aedgeL, Wm, asrcm, adstm, WL, asrcL, adstL,
        etab, wsmb, wdmb, WLt, aS48, aD48);
    k_casts<<<(BM_END + 255) / 256, B256, 0, stream>>>(x, W0, Wm, xb, B0t, Bmt);

    int mblk = (NN + 127) / 128;  // 157

    // ---- conv0 ----
    {
        dim3 g(mblk, 4);
        k_mfma_gemm<<<g, 256, 0, stream>>>(xb, B0t, NN, FIN, 512, h0b, asrc0, adst0, es, ed);
        k_agg0_f<<<NN, 64, 0, stream>>>(rowptr, srcp, etpp, distwp, es, ed, etab + 0,
                                        h0b, b0, xbuf);
        k_bnstats_at<<<200, 128, 0, stream>>>(xbuf, sums);  // slot 0
    }

    // ---- 3 middle convs ----
    int gmid = (NN + 63) / 64;  // 313
    for (int i = 0; i < 3; ++i) {
        k_bnaps<<<NN, 64, 0, stream>>>(xbuf, sums + i * 256, bng + i * 128, bnb + i * 128,
                                       wsmb + i * 512, wdmb + i * 512, hb, hbb, es, ed);
        k_aggmid_f<<<NN, 64, 0, stream>>>(rowptr, srcp, etpp, distwp, es, ed,
                                          etab + (1 + i) * 160, hbb, h0b);
        k_gemm_mid<<<gmid, 128, 0, stream>>>(h0b, Bmt + (size_t)i * HIDD * 512, xbuf,
                                             bm + i * 128, hb, sums + (i + 1) * 256);
    }

    // ---- final conv ----
    {
        k_bnaps<<<NN, 64, 0, stream>>>(xbuf, sums + 3 * 256, bng + 3 * 128, bnb + 3 * 128,
                                       nullptr, nullptr, hb, hbb, es, ed);
        k_gemmL_mfma<<<(NN + 63) / 64, 256, 0, stream>>>(hbb, WLt, hL, aS48, aD48, es, ed);
        k_aggL_f<<<NN, 64, 0, stream>>>(rowptr, srcp, etpp, distwp, es, ed, etab + 4 * 160,
                                        hL, bL, out);
    }
}